// Round 3
// baseline (9301.582 us; speedup 1.0000x reference)
//
#include <hip/hip_runtime.h>
#include <cstdint>
#include <cstddef>

// ---------------------------------------------------------------------------
// dividedSpaceTimeAttention — MI355X (gfx950), runtime-detected f32/bf16 I/O,
// bf16 intermediates, fp32 accumulate.
//
// Structure exploited:
//  * ti rows repeat with period 195  -> second-stage GEMMs use 1560 rows only
//  * final output has 17 distinct rows per batch -> Wf GEMM is 136x768 + scatter
//  * projections: z0 = Wq/bq, z1 = Wk/bk, z2 = Wv/bv
//      stage1: q=rope(z0[1:]), k=rope(z2[1:]), v=z1[1:]; cls: q=z0 row0, k=z1, v=z2
//      stage2: q2=z0, v2=z1, k2=z2   (same swap as reference)
//
// R1: per-batch phase A + aliased phase B -> peak ws ~62 MB (crash fixed).
// R2: NaN root-caused to reading float32 inputs as bf16. Runtime dtype
//     detection; raw-input consumers + output scatter branch on the flag.
// ---------------------------------------------------------------------------

typedef unsigned short u16;
typedef __attribute__((ext_vector_type(8))) short short8;   // 8 x bf16 raw
typedef __attribute__((ext_vector_type(4))) float f32x4;

#define DEV static __device__ __forceinline__

DEV float b2f(u16 u) { union { unsigned int i; float f; } v; v.i = ((unsigned int)u) << 16; return v.f; }
DEV float b2fs(short s) { return b2f((u16)s); }
DEV u16 f2b(float f) {
    union { float f; unsigned int i; } v; v.f = f;
    unsigned int r = v.i + 0x7fffu + ((v.i >> 16) & 1u);   // RNE
    return (u16)(r >> 16);
}

constexpr int   ROWS  = 3137;               // SEQ+1
constexpr int   NPm1  = 195;
constexpr int   MT    = 8 * NPm1;           // 1560
constexpr int   N3    = 2304;               // NH*D3 == 3*DIM
constexpr float SCALE = 1.0f / 96.0f;       // 1/(sqrt(64)*12)
constexpr size_t PZb  = (size_t)ROWS * N3;  // per-batch z-slab stride of P
constexpr size_t P2Z  = (size_t)MT * N3;    // z-slab stride of P2

// --------------------------- reductions (wave64) ---------------------------
DEV float wave_max(float v) {
#pragma unroll
    for (int off = 32; off; off >>= 1) v = fmaxf(v, __shfl_xor(v, off));
    return v;
}
DEV float wave_sum(float v) {
#pragma unroll
    for (int off = 32; off; off >>= 1) v += __shfl_xor(v, off);
    return v;
}
DEV float block_max256(float v, float* red) {
    v = wave_max(v);
    __syncthreads();
    if ((threadIdx.x & 63) == 0) red[threadIdx.x >> 6] = v;
    __syncthreads();
    return fmaxf(fmaxf(red[0], red[1]), fmaxf(red[2], red[3]));
}
float DEV block_sum256(float v, float* red) {
    v = wave_sum(v);
    __syncthreads();
    if ((threadIdx.x & 63) == 0) red[threadIdx.x >> 6] = v;
    __syncthreads();
    return (red[0] + red[1]) + (red[2] + red[3]);
}

// ----------------------------- dtype detection -----------------------------
// bf16 data (N(0,1) scale) never has |v| >= 128; f32 low half-words do ~47%.
__global__ __launch_bounds__(256) void detect_dtype(const u16* __restrict__ x,
                                                    int* __restrict__ flag) {
    __shared__ int cnt;
    if (threadIdx.x == 0) cnt = 0;
    __syncthreads();
    int c = 0;
    for (int i = threadIdx.x; i < 8192; i += 256) {
        unsigned e = (x[i] >> 7) & 0xFFu;
        if (e >= 134u) c++;
    }
#pragma unroll
    for (int off = 32; off; off >>= 1) c += __shfl_xor(c, off);
    if ((threadIdx.x & 63) == 0) atomicAdd(&cnt, c);
    __syncthreads();
    if (threadIdx.x == 0) *flag = (cnt > 16) ? 1 : 0;
}

// ------------------------------- transpose ---------------------------------
// out[c*R + r] = bf16(in[r*C + c]); in is raw input (dtype per flag)
__global__ __launch_bounds__(256) void transpose_k(const void* __restrict__ in,
                                                   u16* __restrict__ out, int R, int C,
                                                   const int* __restrict__ dflag) {
    const int fl = *dflag;
    __shared__ u16 t[32][33];
    int bx = blockIdx.x * 32;   // col
    int by = blockIdx.y * 32;   // row
    int tx = threadIdx.x & 31, ty = threadIdx.x >> 5;
#pragma unroll
    for (int i = 0; i < 32; i += 8) {
        int r = by + ty + i, c = bx + tx;
        if (r < R && c < C) {
            size_t idx = (size_t)r * C + c;
            t[ty + i][tx] = fl ? f2b(((const float*)in)[idx]) : ((const u16*)in)[idx];
        }
    }
    __syncthreads();
#pragma unroll
    for (int i = 0; i < 32; i += 8) {
        int c = bx + ty + i, r = by + tx;
        if (c < C && r < R) out[(size_t)c * R + r] = t[tx][ty + i];
    }
}

// --------------------------------- GEMM ------------------------------------
// C[z] = A(MxK) @ BT[z](NxK)^T + bias[z].  A: raw (f32/bf16 per flag) if araw,
// else ws bf16.  BT: ws bf16.  bias: raw.  C: bf16, or f32 if cf32.
DEV short8 pack_f32x8(const float* p) {
    const float4 u0 = *(const float4*)p;
    const float4 u1 = *(const float4*)(p + 4);
    short8 r;
    r[0] = (short)f2b(u0.x); r[1] = (short)f2b(u0.y);
    r[2] = (short)f2b(u0.z); r[3] = (short)f2b(u0.w);
    r[4] = (short)f2b(u1.x); r[5] = (short)f2b(u1.y);
    r[6] = (short)f2b(u1.z); r[7] = (short)f2b(u1.w);
    return r;
}

__global__ __launch_bounds__(256) void gemm_bt(const void* __restrict__ A, size_t aoff,
                                               const u16* __restrict__ BT,
                                               const void* __restrict__ b0,
                                               const void* __restrict__ b1,
                                               const void* __restrict__ b2,
                                               void* __restrict__ C,
                                               int M, int N, int K,
                                               const int* __restrict__ dflag,
                                               int araw, int cf32) {
    const int fl = *dflag;
    const int af32 = araw && fl;
    const int z = blockIdx.z;
    const u16* Bz = BT + (size_t)z * N * K;
    const void* bias = (z == 0) ? b0 : (z == 1) ? b1 : b2;

    __shared__ u16 As[128 * 32];
    __shared__ u16 Bs[128 * 32];

    const int tid  = threadIdx.x;
    const int lane = tid & 63;
    const int wave = tid >> 6;
    const int wm   = wave & 1;
    const int wn   = wave >> 1;
    const int quad = lane >> 4;
    const int l16  = lane & 15;

    const int m0 = blockIdx.y * 128;
    const int n0 = blockIdx.x * 128;

    const int r0 = tid >> 2;            // 0..63
    const int kp = (tid & 3) << 3;      // 0,8,16,24

    int ga0 = m0 + r0;       if (ga0 > M - 1) ga0 = M - 1;
    int ga1 = m0 + r0 + 64;  if (ga1 > M - 1) ga1 = M - 1;
    const size_t arow0 = aoff + (size_t)ga0 * K + kp;
    const size_t arow1 = aoff + (size_t)ga1 * K + kp;
    const u16* Bp0 = Bz + (size_t)(n0 + r0) * K + kp;
    const u16* Bp1 = Bz + (size_t)(n0 + r0 + 64) * K + kp;

    f32x4 acc[4][4] = {};

    for (int k0 = 0; k0 < K; k0 += 32) {
        short8 a0, a1;
        if (af32) {
            a0 = pack_f32x8((const float*)A + arow0 + k0);
            a1 = pack_f32x8((const float*)A + arow1 + k0);
        } else {
            a0 = *(const short8*)((const u16*)A + arow0 + k0);
            a1 = *(const short8*)((const u16*)A + arow1 + k0);
        }
        short8 bv0 = *(const short8*)(Bp0 + k0);
        short8 bv1 = *(const short8*)(Bp1 + k0);
        __syncthreads();
        *(short8*)(&As[r0 * 32 + kp])        = a0;
        *(short8*)(&As[(r0 + 64) * 32 + kp]) = a1;
        *(short8*)(&Bs[r0 * 32 + kp])        = bv0;
        *(short8*)(&Bs[(r0 + 64) * 32 + kp]) = bv1;
        __syncthreads();

        short8 af[4], bfr[4];
#pragma unroll
        for (int i = 0; i < 4; i++)
            af[i] = *(const short8*)(&As[(wm * 64 + i * 16 + l16) * 32 + quad * 8]);
#pragma unroll
        for (int j = 0; j < 4; j++)
            bfr[j] = *(const short8*)(&Bs[(wn * 64 + j * 16 + l16) * 32 + quad * 8]);
#pragma unroll
        for (int i = 0; i < 4; i++)
#pragma unroll
            for (int j = 0; j < 4; j++)
                acc[i][j] = __builtin_amdgcn_mfma_f32_16x16x32_bf16(af[i], bfr[j], acc[i][j], 0, 0, 0);
    }

    // epilogue: D row = quad*4 + r (m), col = l16 (n)
#pragma unroll
    for (int j = 0; j < 4; j++) {
        int col = n0 + wn * 64 + j * 16 + l16;
        float bb = fl ? ((const float*)bias)[col] : b2f(((const u16*)bias)[col]);
#pragma unroll
        for (int i = 0; i < 4; i++) {
            int rowb = m0 + wm * 64 + i * 16 + quad * 4;
#pragma unroll
            for (int r = 0; r < 4; r++) {
                int row = rowb + r;
                if (row < M) {
                    size_t idx = (size_t)z * M * N + (size_t)row * N + col;
                    float v = acc[i][j][r] + bb;
                    if (cf32) ((float*)C)[idx] = v;
                    else      ((u16*)C)[idx]  = f2b(v);
                }
            }
        }
    }
}

// ------------------------------ cls attention ------------------------------
// grid (12): h.  q = z0 row0; keys = z1 all 3137 rows; values = z2.
__global__ __launch_bounds__(256) void cls_attn(const u16* __restrict__ Pb,
                                                u16* __restrict__ Fmat, int b) {
    int h = blockIdx.x;
    __shared__ float qs[192];
    __shared__ float sc[ROWS];
    __shared__ float red[4];
    int tid = threadIdx.x;
    const size_t base = (size_t)h * 192;
    const u16* Pq  = Pb;            // z0
    const u16* Pkc = Pb + PZb;      // z1 (Wk) -> k_cls
    const u16* Pvc = Pb + 2 * PZb;  // z2 (Wv) -> v_cls

    if (tid < 192) qs[tid] = b2f(Pq[base + tid]);
    __syncthreads();

    float pmax = -1e30f;
    for (int r = tid; r < ROWS; r += 256) {
        const u16* kr = Pkc + base + (size_t)r * N3;
        float s = 0.f;
        for (int d0 = 0; d0 < 192; d0 += 8) {
            short8 v8 = *(const short8*)(kr + d0);
#pragma unroll
            for (int j = 0; j < 8; j++) s += qs[d0 + j] * b2fs(v8[j]);
        }
        s *= SCALE;
        sc[r] = s;
        pmax = fmaxf(pmax, s);
    }
    float m = block_max256(pmax, red);
    float psum = 0.f;
    for (int r = tid; r < ROWS; r += 256) {
        float e = __expf(sc[r] - m);
        sc[r] = e;
        psum += e;
    }
    float S = block_sum256(psum, red);   // barriers inside make sc[] visible

    if (tid < 192) {
        float acc = 0.f;
        const u16* vb = Pvc + base + tid;
        for (int r = 0; r < ROWS; r++) acc += sc[r] * b2f(vb[(size_t)r * N3]);
        Fmat[(size_t)(b * 17) * N3 + (size_t)h * 192 + tid] = f2b(acc / S);
    }
}

// --------------------------- temporal attention ----------------------------
// grid (195, 12): p-1, h.  16x16 attention over frames, rope on q,k.
__global__ __launch_bounds__(128) void temporal_attn(const u16* __restrict__ Pb,
                                                     u16* __restrict__ tmp, int b) {
    int p = blockIdx.x + 1, h = blockIdx.y;
    __shared__ float Qs[16][192];
    __shared__ float Ks[16][192];
    __shared__ float Sm[16][17];
    __shared__ float w[16];
    int tid = threadIdx.x;
    const u16* Pq = Pb;            // z0 -> q
    const u16* Pk = Pb + 2 * PZb;  // z2 (Wv) -> k
    const u16* Pv = Pb + PZb;      // z1 (Wk) -> v

    for (int t = tid; t < 3072; t += 128) {
        int mat = (t >= 1536);
        int i = mat ? t - 1536 : t;
        int f = i / 96;
        int d = (i % 96) * 2;
        int s = f * 196 + p;                      // rope position
        size_t idx = (size_t)(1 + s) * N3 + (size_t)h * 192 + d;
        const u16* src = mat ? Pk : Pq;
        float x1 = b2f(src[idx]), x2 = b2f(src[idx + 1]);
        if (d < 64) {
            float inv = 1.0f / powf(10000.0f, (float)d * (1.0f / 64.0f));
            float ang = (float)s * inv;
            float sn, cs;
            sincosf(ang, &sn, &cs);
            float y1 = x1 * cs - x2 * sn;
            float y2 = x2 * cs + x1 * sn;
            x1 = y1; x2 = y2;
        }
        if (mat) { Ks[f][d] = x1; Ks[f][d + 1] = x2; }
        else     { Qs[f][d] = x1; Qs[f][d + 1] = x2; }
    }
    __syncthreads();

    for (int t = tid; t < 256; t += 128) {
        int f = t >> 4, g = t & 15;
        float s = 0.f;
#pragma unroll 8
        for (int d = 0; d < 192; d++) s += Qs[f][d] * Ks[g][d];
        Sm[f][g] = s * SCALE;
    }
    __syncthreads();
    if (tid < 16) {                 // row softmax
        float m = -1e30f;
#pragma unroll
        for (int g = 0; g < 16; g++) m = fmaxf(m, Sm[tid][g]);
        float S = 0.f;
#pragma unroll
        for (int g = 0; g < 16; g++) { float e = __expf(Sm[tid][g] - m); Sm[tid][g] = e; S += e; }
        float inv = 1.0f / S;
#pragma unroll
        for (int g = 0; g < 16; g++) Sm[tid][g] *= inv;
    }
    __syncthreads();
    if (tid < 16) {                 // column sums (sum over query frames)
        float s = 0.f;
#pragma unroll
        for (int f = 0; f < 16; f++) s += Sm[f][tid];
        w[tid] = s;
    }
    __syncthreads();
    for (int d = tid; d < 192; d += 128) {
        float acc = 0.f;
#pragma unroll
        for (int g = 0; g < 16; g++) {
            size_t idx = (size_t)(1 + g * 196 + p) * N3 + (size_t)h * 192 + d;
            acc += w[g] * b2f(Pv[idx]);
        }
        tmp[(size_t)(b * NPm1 + p - 1) * N3 + (size_t)h * 192 + d] = f2b(acc);
    }
}

// ---------------------------- second attention -----------------------------
// grid (16, 12, 8): xi, h, b.  queries f=0..195 -> row (xi+f)%195;
// keys: xi==0 -> g%195 (196 keys); xi>=1 -> xi+g (16 keys). Sum over queries.
__global__ __launch_bounds__(256) void attn2(const u16* __restrict__ P2,
                                             u16* __restrict__ Fmat) {
    int xi = blockIdx.x, h = blockIdx.y, b = blockIdx.z;
    int Nk = (xi == 0) ? 196 : 16;
    __shared__ float qs[192];
    __shared__ float w[196];
    __shared__ float red[4];
    int tid = threadIdx.x;
    const u16* Q  = P2;             // z0 -> q2
    const u16* V  = P2 + P2Z;       // z1 (Wk) -> v2
    const u16* Kc = P2 + 2 * P2Z;   // z2 (Wv) -> k2
    const size_t hb = (size_t)b * NPm1 * N3 + (size_t)h * 192;

    if (tid < 196) w[tid] = 0.f;
    int g = tid;
    int krow = 0;
    if (g < Nk) krow = (xi == 0) ? (g % 195) : (xi + g);

    for (int f = 0; f < 196; f++) {
        int qrow = (xi + f) % 195;
        __syncthreads();
        if (tid < 192) qs[tid] = b2f(Q[hb + (size_t)qrow * N3 + tid]);
        __syncthreads();
        float sval = -1e30f;
        if (g < Nk) {
            const u16* kr = Kc + hb + (size_t)krow * N3;
            float s = 0.f;
            for (int d0 = 0; d0 < 192; d0 += 8) {
                short8 v8 = *(const short8*)(kr + d0);
#pragma unroll
                for (int j = 0; j < 8; j++) s += qs[d0 + j] * b2fs(v8[j]);
            }
            sval = s * SCALE;
        }
        float m = block_max256(sval, red);
        float e = (g < Nk) ? __expf(sval - m) : 0.f;
        float S = block_sum256(e, red);
        if (g < Nk) w[g] += e / S;
    }
    __syncthreads();
    if (tid < 192) {
        float acc = 0.f;
        for (int gg = 0; gg < Nk; gg++) {
            int kr = (xi == 0) ? (gg % 195) : (xi + gg);
            acc += w[gg] * b2f(V[hb + (size_t)kr * N3 + tid]);
        }
        Fmat[(size_t)(b * 17 + 1 + xi) * N3 + (size_t)h * 192 + tid] = f2b(acc);
    }
}

// ------------------------------ final scatter ------------------------------
// out[b, s, :] = F17[b*17 + (s==0 ? 0 : 1 + (s-1)%16), :]; F17 is f32 in ws.
__global__ __launch_bounds__(256) void scatter_out(const float* __restrict__ F17,
                                                   void* __restrict__ out,
                                                   const int* __restrict__ dflag) {
    const int fl = *dflag;
    int t = blockIdx.x * 256 + threadIdx.x;   // < 8*3137*96 exactly
    int c = t % 96;
    int rem = t / 96;
    int s = rem % ROWS;
    int b = rem / ROWS;
    int src = b * 17 + (s == 0 ? 0 : 1 + ((s - 1) & 15));
    const float* sp = F17 + ((size_t)src * 96 + c) * 8;
    if (fl) {
        float* o = (float*)out + (size_t)t * 8;
        *(float4*)o       = *(const float4*)sp;
        *(float4*)(o + 4) = *(const float4*)(sp + 4);
    } else {
        u16* o = (u16*)out + (size_t)t * 8;
        short8 v;
#pragma unroll
        for (int j = 0; j < 8; j++) v[j] = (short)f2b(sp[j]);
        *(short8*)o = v;
    }
}

// ------------------------------ host launcher ------------------------------
extern "C" void kernel_launch(void* const* d_in, const int* in_sizes, int n_in,
                              void* d_out, int out_size, void* d_ws, size_t ws_size,
                              hipStream_t stream) {
    const void* x   = d_in[0];
    const void* Wq  = d_in[1];
    const void* bq  = d_in[2];
    const void* Wk  = d_in[3];
    const void* bk  = d_in[4];
    const void* Wv  = d_in[5];
    const void* bv  = d_in[6];
    const void* Wt  = d_in[7];
    const void* bt  = d_in[8];
    const void* Wf  = d_in[9];
    const void* bfb = d_in[10];
    (void)in_sizes; (void)n_in; (void)out_size;

    // ---- workspace layout (bytes, 256-aligned) ----
    char* ws = (char*)d_ws;
    size_t off = 0;
    auto allocB = [&](size_t bytes) {
        char* p = ws + off;
        off += (bytes + 255) & ~(size_t)255;
        return p;
    };
    int* dflag = (int*)allocB(256);
    u16* WT    = (u16*)allocB((size_t)3 * N3 * 768 * 2);   // 10.6 MB
    u16* tmp   = (u16*)allocB((size_t)MT * N3 * 2);        //  7.2 MB
    u16* Fmat  = (u16*)allocB((size_t)136 * N3 * 2);       //  0.63 MB
    size_t aliasOff = off;
    u16* Pb    = (u16*)allocB(3 * PZb * 2);                // 43.4 MB (phase A)
    size_t endA = off;
    off = aliasOff;                                         // phase B aliases
    u16*   P2  = (u16*)allocB(3 * P2Z * 2);                // 21.6 MB
    u16*   tiu = (u16*)allocB((size_t)MT * 768 * 2);       //  2.4 MB
    u16*   WtT = (u16*)allocB((size_t)768 * N3 * 2);       //  3.5 MB
    u16*   WfT = (u16*)allocB((size_t)768 * N3 * 2);       //  3.5 MB
    float* F17 = (float*)allocB((size_t)136 * 768 * 4);    //  0.42 MB
    size_t need = (endA > off ? endA : off);
    if (ws_size < need) return;   // graceful mismatch instead of fault

    detect_dtype<<<dim3(1), 256, 0, stream>>>((const u16*)x, dflag);

    // weight transposes needed in phase A
    transpose_k<<<dim3(72, 24), 256, 0, stream>>>(Wq, WT, 768, N3, dflag);
    transpose_k<<<dim3(72, 24), 256, 0, stream>>>(Wk, WT + (size_t)N3 * 768, 768, N3, dflag);
    transpose_k<<<dim3(72, 24), 256, 0, stream>>>(Wv, WT + (size_t)2 * N3 * 768, 768, N3, dflag);

    // ---- phase A: per batch, project x_b then consume with attention ----
    for (int b = 0; b < 8; b++) {
        size_t aoff = (size_t)b * ROWS * 768;
        gemm_bt<<<dim3(18, 25, 3), 256, 0, stream>>>(x, aoff, WT, bq, bk, bv, Pb,
                                                     ROWS, N3, 768, dflag, 1, 0);
        cls_attn<<<dim3(12), 256, 0, stream>>>(Pb, Fmat, b);
        temporal_attn<<<dim3(195, 12), 128, 0, stream>>>(Pb, tmp, b);
    }

    // ---- phase B ----
    transpose_k<<<dim3(24, 72), 256, 0, stream>>>(Wt, WtT, N3, 768, dflag);
    transpose_k<<<dim3(24, 72), 256, 0, stream>>>(Wf, WfT, N3, 768, dflag);

    // tiu = tmp @ Wt + bt   (M=1560, N=768, K=2304)
    gemm_bt<<<dim3(6, 13, 1), 256, 0, stream>>>(tmp, 0, WtT, bt, bt, bt, tiu,
                                                MT, 768, N3, dflag, 0, 0);
    // P2[z] = tiu @ W{q,k,v} + b   (M=1560, N=2304, K=768)
    gemm_bt<<<dim3(18, 13, 3), 256, 0, stream>>>(tiu, 0, WT, bq, bk, bv, P2,
                                                 MT, N3, 768, dflag, 0, 0);

    attn2<<<dim3(16, 12, 8), 256, 0, stream>>>(P2, Fmat);

    // F17 = Fmat @ Wf + bf   (M=136, N=768, K=2304) -> f32
    gemm_bt<<<dim3(6, 2, 1), 256, 0, stream>>>(Fmat, 0, WfT, bfb, bfb, bfb, F17,
                                               136, 768, N3, dflag, 0, 1);

    scatter_out<<<dim3(9411), 256, 0, stream>>>(F17, d_out, dflag);
}

// Round 4
// 2077.172 us; speedup vs baseline: 4.4780x; 4.4780x over previous
//
#include <hip/hip_runtime.h>
#include <cstdint>
#include <cstddef>

// ---------------------------------------------------------------------------
// dividedSpaceTimeAttention — MI355X (gfx950), runtime-detected f32/bf16 I/O,
// bf16 intermediates, fp32 accumulate.
//
// R1: per-batch phase A + aliased phase B -> peak ws ~66 MB.
// R2: NaN root-caused to f32 inputs read as bf16 -> runtime dtype detection.
// R3: passed, 9.3 ms. attn2 = 4.45 ms (serial f-loop, MfmaUtil 0).
// R4: attn2 -> MFMA-batched scores + register softmax (no serial loop);
//     cls_attn -> 32-way row split + merge; rope trig -> precomputed table.
// ---------------------------------------------------------------------------

typedef unsigned short u16;
typedef __attribute__((ext_vector_type(8))) short short8;   // 8 x bf16 raw
typedef __attribute__((ext_vector_type(4))) float f32x4;

#define DEV static __device__ __forceinline__

DEV float b2f(u16 u) { union { unsigned int i; float f; } v; v.i = ((unsigned int)u) << 16; return v.f; }
DEV float b2fs(short s) { return b2f((u16)s); }
DEV u16 f2b(float f) {
    union { float f; unsigned int i; } v; v.f = f;
    unsigned int r = v.i + 0x7fffu + ((v.i >> 16) & 1u);   // RNE
    return (u16)(r >> 16);
}

constexpr int   ROWS  = 3137;               // SEQ+1
constexpr int   NPm1  = 195;
constexpr int   MT    = 8 * NPm1;           // 1560
constexpr int   N3    = 2304;               // NH*D3 == 3*DIM
constexpr float SCALE = 1.0f / 96.0f;       // 1/(sqrt(64)*12)
constexpr size_t PZb  = (size_t)ROWS * N3;  // per-batch z-slab stride of P
constexpr size_t P2Z  = (size_t)MT * N3;    // z-slab stride of P2
constexpr int   CLS_NS = 32;                // cls row splits
constexpr int   CLS_RS = 99;                // rows per split (32*99 >= 3137)

// --------------------------- reductions (wave64) ---------------------------
DEV float wave_max(float v) {
#pragma unroll
    for (int off = 32; off; off >>= 1) v = fmaxf(v, __shfl_xor(v, off));
    return v;
}
DEV float wave_sum(float v) {
#pragma unroll
    for (int off = 32; off; off >>= 1) v += __shfl_xor(v, off);
    return v;
}
DEV float block_max256(float v, float* red) {
    v = wave_max(v);
    __syncthreads();
    if ((threadIdx.x & 63) == 0) red[threadIdx.x >> 6] = v;
    __syncthreads();
    return fmaxf(fmaxf(red[0], red[1]), fmaxf(red[2], red[3]));
}
DEV float block_sum256(float v, float* red) {
    v = wave_sum(v);
    __syncthreads();
    if ((threadIdx.x & 63) == 0) red[threadIdx.x >> 6] = v;
    __syncthreads();
    return (red[0] + red[1]) + (red[2] + red[3]);
}

// ----------------------------- dtype detection -----------------------------
__global__ __launch_bounds__(256) void detect_dtype(const u16* __restrict__ x,
                                                    int* __restrict__ flag) {
    __shared__ int cnt;
    if (threadIdx.x == 0) cnt = 0;
    __syncthreads();
    int c = 0;
    for (int i = threadIdx.x; i < 8192; i += 256) {
        unsigned e = (x[i] >> 7) & 0xFFu;
        if (e >= 134u) c++;
    }
#pragma unroll
    for (int off = 32; off; off >>= 1) c += __shfl_xor(c, off);
    if ((threadIdx.x & 63) == 0) atomicAdd(&cnt, c);
    __syncthreads();
    if (threadIdx.x == 0) *flag = (cnt > 16) ? 1 : 0;
}

// ------------------------------- transpose ---------------------------------
__global__ __launch_bounds__(256) void transpose_k(const void* __restrict__ in,
                                                   u16* __restrict__ out, int R, int C,
                                                   const int* __restrict__ dflag) {
    const int fl = *dflag;
    __shared__ u16 t[32][33];
    int bx = blockIdx.x * 32;   // col
    int by = blockIdx.y * 32;   // row
    int tx = threadIdx.x & 31, ty = threadIdx.x >> 5;
#pragma unroll
    for (int i = 0; i < 32; i += 8) {
        int r = by + ty + i, c = bx + tx;
        if (r < R && c < C) {
            size_t idx = (size_t)r * C + c;
            t[ty + i][tx] = fl ? f2b(((const float*)in)[idx]) : ((const u16*)in)[idx];
        }
    }
    __syncthreads();
#pragma unroll
    for (int i = 0; i < 32; i += 8) {
        int c = bx + ty + i, r = by + tx;
        if (c < C && r < R) out[(size_t)c * R + r] = t[tx][ty + i];
    }
}

// ------------------------------ rope tables --------------------------------
// tab[(s*32+i)*2] = cos(s*invf(i)), +1 = sin.  s in [0,3136), i pair index.
__global__ __launch_bounds__(256) void rope_tab_k(float* __restrict__ tab) {
    int t = blockIdx.x * 256 + threadIdx.x;           // < 3136*32
    if (t >= 3136 * 32) return;
    int s = t >> 5, i = t & 31;
    float inv = powf(10000.0f, -(float)(2 * i) * (1.0f / 64.0f));
    float sn, cs;
    sincosf((float)s * inv, &sn, &cs);
    tab[t * 2]     = cs;
    tab[t * 2 + 1] = sn;
}

// --------------------------------- GEMM ------------------------------------
DEV short8 pack_f32x8(const float* p) {
    const float4 u0 = *(const float4*)p;
    const float4 u1 = *(const float4*)(p + 4);
    short8 r;
    r[0] = (short)f2b(u0.x); r[1] = (short)f2b(u0.y);
    r[2] = (short)f2b(u0.z); r[3] = (short)f2b(u0.w);
    r[4] = (short)f2b(u1.x); r[5] = (short)f2b(u1.y);
    r[6] = (short)f2b(u1.z); r[7] = (short)f2b(u1.w);
    return r;
}

__global__ __launch_bounds__(256) void gemm_bt(const void* __restrict__ A, size_t aoff,
                                               const u16* __restrict__ BT,
                                               const void* __restrict__ b0,
                                               const void* __restrict__ b1,
                                               const void* __restrict__ b2,
                                               void* __restrict__ C,
                                               int M, int N, int K,
                                               const int* __restrict__ dflag,
                                               int araw, int cf32) {
    const int fl = *dflag;
    const int af32 = araw && fl;
    const int z = blockIdx.z;
    const u16* Bz = BT + (size_t)z * N * K;
    const void* bias = (z == 0) ? b0 : (z == 1) ? b1 : b2;

    __shared__ u16 As[128 * 32];
    __shared__ u16 Bs[128 * 32];

    const int tid  = threadIdx.x;
    const int lane = tid & 63;
    const int wave = tid >> 6;
    const int wm   = wave & 1;
    const int wn   = wave >> 1;
    const int quad = lane >> 4;
    const int l16  = lane & 15;

    const int m0 = blockIdx.y * 128;
    const int n0 = blockIdx.x * 128;

    const int r0 = tid >> 2;            // 0..63
    const int kp = (tid & 3) << 3;      // 0,8,16,24

    int ga0 = m0 + r0;       if (ga0 > M - 1) ga0 = M - 1;
    int ga1 = m0 + r0 + 64;  if (ga1 > M - 1) ga1 = M - 1;
    const size_t arow0 = aoff + (size_t)ga0 * K + kp;
    const size_t arow1 = aoff + (size_t)ga1 * K + kp;
    const u16* Bp0 = Bz + (size_t)(n0 + r0) * K + kp;
    const u16* Bp1 = Bz + (size_t)(n0 + r0 + 64) * K + kp;

    f32x4 acc[4][4] = {};

    for (int k0 = 0; k0 < K; k0 += 32) {
        short8 a0, a1;
        if (af32) {
            a0 = pack_f32x8((const float*)A + arow0 + k0);
            a1 = pack_f32x8((const float*)A + arow1 + k0);
        } else {
            a0 = *(const short8*)((const u16*)A + arow0 + k0);
            a1 = *(const short8*)((const u16*)A + arow1 + k0);
        }
        short8 bv0 = *(const short8*)(Bp0 + k0);
        short8 bv1 = *(const short8*)(Bp1 + k0);
        __syncthreads();
        *(short8*)(&As[r0 * 32 + kp])        = a0;
        *(short8*)(&As[(r0 + 64) * 32 + kp]) = a1;
        *(short8*)(&Bs[r0 * 32 + kp])        = bv0;
        *(short8*)(&Bs[(r0 + 64) * 32 + kp]) = bv1;
        __syncthreads();

        short8 af[4], bfr[4];
#pragma unroll
        for (int i = 0; i < 4; i++)
            af[i] = *(const short8*)(&As[(wm * 64 + i * 16 + l16) * 32 + quad * 8]);
#pragma unroll
        for (int j = 0; j < 4; j++)
            bfr[j] = *(const short8*)(&Bs[(wn * 64 + j * 16 + l16) * 32 + quad * 8]);
#pragma unroll
        for (int i = 0; i < 4; i++)
#pragma unroll
            for (int j = 0; j < 4; j++)
                acc[i][j] = __builtin_amdgcn_mfma_f32_16x16x32_bf16(af[i], bfr[j], acc[i][j], 0, 0, 0);
    }

#pragma unroll
    for (int j = 0; j < 4; j++) {
        int col = n0 + wn * 64 + j * 16 + l16;
        float bb = fl ? ((const float*)bias)[col] : b2f(((const u16*)bias)[col]);
#pragma unroll
        for (int i = 0; i < 4; i++) {
            int rowb = m0 + wm * 64 + i * 16 + quad * 4;
#pragma unroll
            for (int r = 0; r < 4; r++) {
                int row = rowb + r;
                if (row < M) {
                    size_t idx = (size_t)z * M * N + (size_t)row * N + col;
                    float v = acc[i][j][r] + bb;
                    if (cf32) ((float*)C)[idx] = v;
                    else      ((u16*)C)[idx]  = f2b(v);
                }
            }
        }
    }
}

// ------------------------- cls attention (split) ---------------------------
// grid (12, 32): h, split.  Partial online-softmax over a 99-row slice.
// part[((b*12+h)*32+split)*194] = {m, l, acc[192]}
__global__ __launch_bounds__(256) void cls_part(const u16* __restrict__ Pb,
                                                float* __restrict__ part, int b) {
    int h = blockIdx.x, sp = blockIdx.y;
    int base = sp * CLS_RS;
    int cnt = ROWS - base; if (cnt > CLS_RS) cnt = CLS_RS;
    __shared__ float qs[192];
    __shared__ float sc[CLS_RS];
    __shared__ float red[4];
    int tid = threadIdx.x;
    const size_t hbase = (size_t)h * 192;
    const u16* Pq  = Pb;            // z0
    const u16* Pkc = Pb + PZb;      // z1 (Wk) -> k_cls
    const u16* Pvc = Pb + 2 * PZb;  // z2 (Wv) -> v_cls

    if (tid < 192) qs[tid] = b2f(Pq[hbase + tid]);
    __syncthreads();

    float sval = -1e30f;
    if (tid < cnt) {
        const u16* kr = Pkc + hbase + (size_t)(base + tid) * N3;
        float s = 0.f;
        for (int d0 = 0; d0 < 192; d0 += 8) {
            short8 v8 = *(const short8*)(kr + d0);
#pragma unroll
            for (int j = 0; j < 8; j++) s += qs[d0 + j] * b2fs(v8[j]);
        }
        sval = s * SCALE;
    }
    float m = block_max256(sval, red);
    float e = (tid < cnt) ? __expf(sval - m) : 0.f;
    float l = block_sum256(e, red);
    if (tid < cnt) sc[tid] = e;
    __syncthreads();

    float* pp = part + ((size_t)(b * 12 + h) * CLS_NS + sp) * 194;
    if (tid == 0) { pp[0] = m; pp[1] = l; }
    if (tid < 192) {
        float acc = 0.f;
        const u16* vb = Pvc + hbase + tid;
        for (int r = 0; r < cnt; r++) acc += sc[r] * b2f(vb[(size_t)(base + r) * N3]);
        pp[2 + tid] = acc;
    }
}

// grid (12, 8): h, b.  Merge 32 partials -> Fmat row b*17.
__global__ __launch_bounds__(192) void cls_merge(const float* __restrict__ part,
                                                 u16* __restrict__ Fmat) {
    int h = blockIdx.x, b = blockIdx.y;
    int tid = threadIdx.x;
    const float* p0 = part + (size_t)(b * 12 + h) * CLS_NS * 194;
    float M = -1e30f;
#pragma unroll
    for (int s = 0; s < CLS_NS; s++) M = fmaxf(M, p0[s * 194]);
    float L = 0.f, acc = 0.f;
#pragma unroll
    for (int s = 0; s < CLS_NS; s++) {
        float w = __expf(p0[s * 194] - M);
        L += w * p0[s * 194 + 1];
        acc += w * p0[s * 194 + 2 + tid];
    }
    Fmat[(size_t)(b * 17) * N3 + (size_t)h * 192 + tid] = f2b(acc / L);
}

// --------------------------- temporal attention ----------------------------
// grid (195, 12): p-1, h.  16x16 attention over frames, rope via table.
__global__ __launch_bounds__(128) void temporal_attn(const u16* __restrict__ Pb,
                                                     const float* __restrict__ tab,
                                                     u16* __restrict__ tmp, int b) {
    int p = blockIdx.x + 1, h = blockIdx.y;
    __shared__ float Qs[16][192];
    __shared__ float Ks[16][192];
    __shared__ float Sm[16][17];
    __shared__ float w[16];
    int tid = threadIdx.x;
    const u16* Pq = Pb;            // z0 -> q
    const u16* Pk = Pb + 2 * PZb;  // z2 (Wv) -> k
    const u16* Pv = Pb + PZb;      // z1 (Wk) -> v

    for (int t = tid; t < 3072; t += 128) {
        int mat = (t >= 1536);
        int i = mat ? t - 1536 : t;
        int f = i / 96;
        int d = (i % 96) * 2;
        int s = f * 196 + p;                      // rope position
        size_t idx = (size_t)(1 + s) * N3 + (size_t)h * 192 + d;
        const u16* src = mat ? Pk : Pq;
        float x1 = b2f(src[idx]), x2 = b2f(src[idx + 1]);
        if (d < 64) {
            const float* tp = tab + ((size_t)s * 32 + (d >> 1)) * 2;
            float cs = tp[0], sn = tp[1];
            float y1 = x1 * cs - x2 * sn;
            float y2 = x2 * cs + x1 * sn;
            x1 = y1; x2 = y2;
        }
        if (mat) { Ks[f][d] = x1; Ks[f][d + 1] = x2; }
        else     { Qs[f][d] = x1; Qs[f][d + 1] = x2; }
    }
    __syncthreads();

    for (int t = tid; t < 256; t += 128) {
        int f = t >> 4, g = t & 15;
        float s = 0.f;
#pragma unroll 8
        for (int d = 0; d < 192; d++) s += Qs[f][d] * Ks[g][d];
        Sm[f][g] = s * SCALE;
    }
    __syncthreads();
    if (tid < 16) {
        float m = -1e30f;
#pragma unroll
        for (int g = 0; g < 16; g++) m = fmaxf(m, Sm[tid][g]);
        float S = 0.f;
#pragma unroll
        for (int g = 0; g < 16; g++) { float e = __expf(Sm[tid][g] - m); Sm[tid][g] = e; S += e; }
        float inv = 1.0f / S;
#pragma unroll
        for (int g = 0; g < 16; g++) Sm[tid][g] *= inv;
    }
    __syncthreads();
    if (tid < 16) {
        float s = 0.f;
#pragma unroll
        for (int f = 0; f < 16; f++) s += Sm[f][tid];
        w[tid] = s;
    }
    __syncthreads();
    for (int d = tid; d < 192; d += 128) {
        float acc = 0.f;
#pragma unroll
        for (int g = 0; g < 16; g++) {
            size_t idx = (size_t)(1 + g * 196 + p) * N3 + (size_t)h * 192 + d;
            acc += w[g] * b2f(Pv[idx]);
        }
        tmp[(size_t)(b * NPm1 + p - 1) * N3 + (size_t)h * 192 + d] = f2b(acc);
    }
}

// ---------------------- second attention (MFMA batch) ----------------------
// grid (16, 12, 8): xi, h, b.  196 queries f -> qrow (xi+f)%195;
// keys: xi==0 -> 196 keys g%195; xi>=1 -> 16 keys xi+g.  w[g] = sum_f P[f][g].
template <int NC>
DEV void attn2_tiles(const u16* Q, const u16* K, size_t hb, int xi,
                     int wave, int quad, int l16, float* wsh) {
    for (int tile = wave; tile < 13; tile += 4) {
        int f = tile * 16 + l16;
        int qrow = (xi + f) % 195;
        const u16* qp = Q + hb + (size_t)qrow * N3 + quad * 8;
        short8 Afr[6];
#pragma unroll
        for (int ks = 0; ks < 6; ks++) Afr[ks] = *(const short8*)(qp + ks * 32);

        f32x4 S[NC];
#pragma unroll
        for (int c = 0; c < NC; c++) {
            int g = c * 16 + l16;
            int krow = (NC == 1) ? (xi + l16) : ((g < 196 ? g : 0) % 195);
            const u16* kp = K + hb + (size_t)krow * N3 + quad * 8;
            f32x4 acc = {0.f, 0.f, 0.f, 0.f};
#pragma unroll
            for (int ks = 0; ks < 6; ks++)
                acc = __builtin_amdgcn_mfma_f32_16x16x32_bf16(Afr[ks],
                        *(const short8*)(kp + ks * 32), acc, 0, 0, 0);
            S[c] = acc;
        }
        // scale + key mask
#pragma unroll
        for (int c = 0; c < NC; c++) {
            bool kbad = (NC > 1) && (c * 16 + l16 >= 196);
#pragma unroll
            for (int r = 0; r < 4; r++)
                S[c][r] = kbad ? -1e30f : S[c][r] * SCALE;
        }
        // per-row softmax (row = tile*16 + quad*4 + r; cols across l16 lanes)
#pragma unroll
        for (int r = 0; r < 4; r++) {
            float mr = -1e30f;
#pragma unroll
            for (int c = 0; c < NC; c++) mr = fmaxf(mr, S[c][r]);
#pragma unroll
            for (int k = 1; k < 16; k <<= 1) mr = fmaxf(mr, __shfl_xor(mr, k));
            float lr = 0.f;
#pragma unroll
            for (int c = 0; c < NC; c++) { float e = __expf(S[c][r] - mr); S[c][r] = e; lr += e; }
#pragma unroll
            for (int k = 1; k < 16; k <<= 1) lr += __shfl_xor(lr, k);
            float inv = 1.0f / lr;
            bool qok = (tile * 16 + quad * 4 + r) < 196;
#pragma unroll
            for (int c = 0; c < NC; c++) S[c][r] = qok ? S[c][r] * inv : 0.f;
        }
        // accumulate w over rows: regs + quad shuffles, then LDS atomic
#pragma unroll
        for (int c = 0; c < NC; c++) {
            float wp = S[c][0] + S[c][1] + S[c][2] + S[c][3];
            wp += __shfl_xor(wp, 16);
            wp += __shfl_xor(wp, 32);
            if (quad == 0) atomicAdd(&wsh[c * 16 + l16], wp);
        }
    }
}

__global__ __launch_bounds__(256) void attn2(const u16* __restrict__ P2,
                                             u16* __restrict__ Fmat) {
    int xi = blockIdx.x, h = blockIdx.y, b = blockIdx.z;
    int Nk = (xi == 0) ? 196 : 16;
    __shared__ float wsh[208];
    int tid = threadIdx.x;
    if (tid < 208) wsh[tid] = 0.f;
    __syncthreads();

    const u16* Q  = P2;             // z0 -> q2
    const u16* V  = P2 + P2Z;       // z1 (Wk) -> v2
    const u16* Kc = P2 + 2 * P2Z;   // z2 (Wv) -> k2
    const size_t hb = (size_t)b * NPm1 * N3 + (size_t)h * 192;

    int wave = tid >> 6, lane = tid & 63, quad = lane >> 4, l16 = lane & 15;
    if (xi == 0) attn2_tiles<13>(Q, Kc, hb, xi, wave, quad, l16, wsh);
    else         attn2_tiles<1>(Q, Kc, hb, xi, wave, quad, l16, wsh);
    __syncthreads();

    if (tid < 192) {
        float acc = 0.f;
        for (int g = 0; g < Nk; g++) {
            int kr = (xi == 0) ? (g % 195) : (xi + g);
            acc += wsh[g] * b2f(V[hb + (size_t)kr * N3 + tid]);
        }
        Fmat[(size_t)(b * 17 + 1 + xi) * N3 + (size_t)h * 192 + tid] = f2b(acc);
    }
}

// ------------------------------ final scatter ------------------------------
__global__ __launch_bounds__(256) void scatter_out(const float* __restrict__ F17,
                                                   void* __restrict__ out,
                                                   const int* __restrict__ dflag) {
    const int fl = *dflag;
    int t = blockIdx.x * 256 + threadIdx.x;   // < 8*3137*96 exactly
    int c = t % 96;
    int rem = t / 96;
    int s = rem % ROWS;
    int b = rem / ROWS;
    int src = b * 17 + (s == 0 ? 0 : 1 + ((s - 1) & 15));
    const float* sp = F17 + ((size_t)src * 96 + c) * 8;
    if (fl) {
        float* o = (float*)out + (size_t)t * 8;
        *(float4*)o       = *(const float4*)sp;
        *(float4*)(o + 4) = *(const float4*)(sp + 4);
    } else {
        u16* o = (u16*)out + (size_t)t * 8;
        short8 v;
#pragma unroll
        for (int j = 0; j < 8; j++) v[j] = (short)f2b(sp[j]);
        *(short8*)o = v;
    }
}

// ------------------------------ host launcher ------------------------------
extern "C" void kernel_launch(void* const* d_in, const int* in_sizes, int n_in,
                              void* d_out, int out_size, void* d_ws, size_t ws_size,
                              hipStream_t stream) {
    const void* x   = d_in[0];
    const void* Wq  = d_in[1];
    const void* bq  = d_in[2];
    const void* Wk  = d_in[3];
    const void* bk  = d_in[4];
    const void* Wv  = d_in[5];
    const void* bv  = d_in[6];
    const void* Wt  = d_in[7];
    const void* bt  = d_in[8];
    const void* Wf  = d_in[9];
    const void* bfb = d_in[10];
    (void)in_sizes; (void)n_in; (void)out_size;

    char* ws = (char*)d_ws;
    size_t off = 0;
    auto allocB = [&](size_t bytes) {
        char* p = ws + off;
        off += (bytes + 255) & ~(size_t)255;
        return p;
    };
    int*   dflag = (int*)allocB(256);
    u16*   WT    = (u16*)allocB((size_t)3 * N3 * 768 * 2);   // 10.6 MB
    u16*   tmp   = (u16*)allocB((size_t)MT * N3 * 2);        //  7.2 MB
    u16*   Fmat  = (u16*)allocB((size_t)136 * N3 * 2);       //  0.63 MB
    float* ropeT = (float*)allocB((size_t)3136 * 32 * 2 * 4);//  0.80 MB
    float* clsP  = (float*)allocB((size_t)8 * 12 * CLS_NS * 194 * 4); // 2.38 MB
    size_t aliasOff = off;
    u16* Pb    = (u16*)allocB(3 * PZb * 2);                // 43.4 MB (phase A)
    size_t endA = off;
    off = aliasOff;                                         // phase B aliases
    u16*   P2  = (u16*)allocB(3 * P2Z * 2);                // 21.6 MB
    u16*   tiu = (u16*)allocB((size_t)MT * 768 * 2);       //  2.4 MB
    u16*   WtT = (u16*)allocB((size_t)768 * N3 * 2);       //  3.5 MB
    u16*   WfT = (u16*)allocB((size_t)768 * N3 * 2);       //  3.5 MB
    float* F17 = (float*)allocB((size_t)136 * 768 * 4);    //  0.42 MB
    size_t need = (endA > off ? endA : off);
    if (ws_size < need) return;   // graceful mismatch instead of fault

    detect_dtype<<<dim3(1), 256, 0, stream>>>((const u16*)x, dflag);
    rope_tab_k<<<dim3(392), 256, 0, stream>>>(ropeT);

    transpose_k<<<dim3(72, 24), 256, 0, stream>>>(Wq, WT, 768, N3, dflag);
    transpose_k<<<dim3(72, 24), 256, 0, stream>>>(Wk, WT + (size_t)N3 * 768, 768, N3, dflag);
    transpose_k<<<dim3(72, 24), 256, 0, stream>>>(Wv, WT + (size_t)2 * N3 * 768, 768, N3, dflag);

    // ---- phase A: per batch, project x_b then consume with attention ----
    for (int b = 0; b < 8; b++) {
        size_t aoff = (size_t)b * ROWS * 768;
        gemm_bt<<<dim3(18, 25, 3), 256, 0, stream>>>(x, aoff, WT, bq, bk, bv, Pb,
                                                     ROWS, N3, 768, dflag, 1, 0);
        cls_part<<<dim3(12, CLS_NS), 256, 0, stream>>>(Pb, clsP, b);
        temporal_attn<<<dim3(195, 12), 128, 0, stream>>>(Pb, ropeT, tmp, b);
    }
    cls_merge<<<dim3(12, 8), 192, 0, stream>>>(clsP, Fmat);

    // ---- phase B ----
    transpose_k<<<dim3(24, 72), 256, 0, stream>>>(Wt, WtT, N3, 768, dflag);
    transpose_k<<<dim3(24, 72), 256, 0, stream>>>(Wf, WfT, N3, 768, dflag);

    gemm_bt<<<dim3(6, 13, 1), 256, 0, stream>>>(tmp, 0, WtT, bt, bt, bt, tiu,
                                                MT, 768, N3, dflag, 0, 0);
    gemm_bt<<<dim3(18, 13, 3), 256, 0, stream>>>(tiu, 0, WT, bq, bk, bv, P2,
                                                 MT, N3, 768, dflag, 0, 0);

    attn2<<<dim3(16, 12, 8), 256, 0, stream>>>(P2, Fmat);

    gemm_bt<<<dim3(6, 2, 1), 256, 0, stream>>>(Fmat, 0, WfT, bfb, bfb, bfb, F17,
                                               136, 768, N3, dflag, 0, 1);

    scatter_out<<<dim3(9411), 256, 0, stream>>>(F17, d_out, dflag);
}

// Round 5
// 1609.731 us; speedup vs baseline: 5.7783x; 1.2904x over previous
//
#include <hip/hip_runtime.h>
#include <cstdint>
#include <cstddef>

// ---------------------------------------------------------------------------
// dividedSpaceTimeAttention — MI355X (gfx950), runtime-detected f32/bf16 I/O,
// bf16 intermediates, fp32 accumulate.
//
// R1: per-batch phase A + aliased phase B -> fits small workspace.
// R2: NaN root-caused to f32 inputs read as bf16 -> runtime dtype detection.
// R3: passed, 9.3 ms (attn2 serial f-loop = 4.45 ms).
// R4: attn2 MFMA-batched -> 2.08 ms; attn2 still top (283 us): xi=0 tail,
//     2.6% occupancy, scattered per-lane global reads.
// R5: attn2 -> tile-parallel LDS-staged (uniform 1248 blocks) + global atomics
//     + tiny epilogue; phase A batched across batches (ws-size tiered);
//     GEMM -> global_load_lds(16B) async staging; x pre-converted to bf16.
// ---------------------------------------------------------------------------

typedef unsigned short u16;
typedef __attribute__((ext_vector_type(8))) short short8;   // 8 x bf16 raw
typedef __attribute__((ext_vector_type(4))) float f32x4;

#define DEV static __device__ __forceinline__
#define AS1 __attribute__((address_space(1)))
#define AS3 __attribute__((address_space(3)))

DEV float b2f(u16 u) { union { unsigned int i; float f; } v; v.i = ((unsigned int)u) << 16; return v.f; }
DEV float b2fs(short s) { return b2f((u16)s); }
DEV u16 f2b(float f) {
    union { float f; unsigned int i; } v; v.f = f;
    unsigned int r = v.i + 0x7fffu + ((v.i >> 16) & 1u);   // RNE
    return (u16)(r >> 16);
}
DEV void gld16(const u16* g, u16* l) {   // async global->LDS, 16 B/lane
    __builtin_amdgcn_global_load_lds((AS1 void*)(g), (AS3 void*)(l), 16, 0, 0);
}

constexpr int   ROWS  = 3137;               // SEQ+1
constexpr int   NPm1  = 195;
constexpr int   MT    = 8 * NPm1;           // 1560
constexpr int   N3    = 2304;               // NH*D3 == 3*DIM
constexpr float SCALE = 1.0f / 96.0f;       // 1/(sqrt(64)*12)
constexpr size_t P2Z  = (size_t)MT * N3;    // z-slab stride of P2
constexpr int   CLS_NS = 32;                // cls row splits
constexpr int   CLS_RS = 99;                // rows per split (32*99 >= 3137)
constexpr int   LDK   = 200;                // padded LDS row stride (u16)

// --------------------------- reductions (wave64) ---------------------------
DEV float wave_max(float v) {
#pragma unroll
    for (int off = 32; off; off >>= 1) v = fmaxf(v, __shfl_xor(v, off));
    return v;
}
DEV float wave_sum(float v) {
#pragma unroll
    for (int off = 32; off; off >>= 1) v += __shfl_xor(v, off);
    return v;
}
DEV float block_max256(float v, float* red) {
    v = wave_max(v);
    __syncthreads();
    if ((threadIdx.x & 63) == 0) red[threadIdx.x >> 6] = v;
    __syncthreads();
    return fmaxf(fmaxf(red[0], red[1]), fmaxf(red[2], red[3]));
}
DEV float block_sum256(float v, float* red) {
    v = wave_sum(v);
    __syncthreads();
    if ((threadIdx.x & 63) == 0) red[threadIdx.x >> 6] = v;
    __syncthreads();
    return (red[0] + red[1]) + (red[2] + red[3]);
}

// ----------------------------- dtype detection -----------------------------
__global__ __launch_bounds__(256) void detect_dtype(const u16* __restrict__ x,
                                                    int* __restrict__ flag) {
    __shared__ int cnt;
    if (threadIdx.x == 0) cnt = 0;
    __syncthreads();
    int c = 0;
    for (int i = threadIdx.x; i < 8192; i += 256) {
        unsigned e = (x[i] >> 7) & 0xFFu;
        if (e >= 134u) c++;
    }
#pragma unroll
    for (int off = 32; off; off >>= 1) c += __shfl_xor(c, off);
    if ((threadIdx.x & 63) == 0) atomicAdd(&cnt, c);
    __syncthreads();
    if (threadIdx.x == 0) *flag = (cnt > 16) ? 1 : 0;
}

// --------------------------- x -> bf16 pre-convert -------------------------
__global__ __launch_bounds__(256) void convert_x(const void* __restrict__ x,
                                                 u16* __restrict__ xb,
                                                 const int* __restrict__ dflag) {
    const int fl = *dflag;
    int t = blockIdx.x * 256 + threadIdx.x;       // < 2409216 exactly
    size_t e0 = (size_t)t * 8;
    if (fl) {
        const float* p = (const float*)x + e0;
        float4 u0 = *(const float4*)p, u1 = *(const float4*)(p + 4);
        short8 r;
        r[0]=(short)f2b(u0.x); r[1]=(short)f2b(u0.y); r[2]=(short)f2b(u0.z); r[3]=(short)f2b(u0.w);
        r[4]=(short)f2b(u1.x); r[5]=(short)f2b(u1.y); r[6]=(short)f2b(u1.z); r[7]=(short)f2b(u1.w);
        *(short8*)(xb + e0) = r;
    } else {
        *(short8*)(xb + e0) = *(const short8*)((const u16*)x + e0);
    }
}

// ------------------------------- transpose ---------------------------------
__global__ __launch_bounds__(256) void transpose_k(const void* __restrict__ in,
                                                   u16* __restrict__ out, int R, int C,
                                                   const int* __restrict__ dflag) {
    const int fl = *dflag;
    __shared__ u16 t[32][33];
    int bx = blockIdx.x * 32, by = blockIdx.y * 32;
    int tx = threadIdx.x & 31, ty = threadIdx.x >> 5;
#pragma unroll
    for (int i = 0; i < 32; i += 8) {
        int r = by + ty + i, c = bx + tx;
        if (r < R && c < C) {
            size_t idx = (size_t)r * C + c;
            t[ty + i][tx] = fl ? f2b(((const float*)in)[idx]) : ((const u16*)in)[idx];
        }
    }
    __syncthreads();
#pragma unroll
    for (int i = 0; i < 32; i += 8) {
        int c = bx + ty + i, r = by + tx;
        if (c < C && r < R) out[(size_t)c * R + r] = t[tx][ty + i];
    }
}

// ------------------------------ rope tables --------------------------------
__global__ __launch_bounds__(256) void rope_tab_k(float* __restrict__ tab) {
    int t = blockIdx.x * 256 + threadIdx.x;           // < 3136*32
    if (t >= 3136 * 32) return;
    int s = t >> 5, i = t & 31;
    float inv = powf(10000.0f, -(float)(2 * i) * (1.0f / 64.0f));
    float sn, cs;
    sincosf((float)s * inv, &sn, &cs);
    tab[t * 2]     = cs;
    tab[t * 2 + 1] = sn;
}

// --------------------------------- GEMM ------------------------------------
// C[z] = A(MxK) @ BT[z](NxK)^T + bias[z].  A bf16 (async LDS staging) unless
// araw&&fl (raw f32 -> pack path).  BT ws bf16.  bias raw.  C bf16 / f32.
DEV short8 pack_f32x8(const float* p) {
    const float4 u0 = *(const float4*)p;
    const float4 u1 = *(const float4*)(p + 4);
    short8 r;
    r[0]=(short)f2b(u0.x); r[1]=(short)f2b(u0.y); r[2]=(short)f2b(u0.z); r[3]=(short)f2b(u0.w);
    r[4]=(short)f2b(u1.x); r[5]=(short)f2b(u1.y); r[6]=(short)f2b(u1.z); r[7]=(short)f2b(u1.w);
    return r;
}

__global__ __launch_bounds__(256) void gemm_bt(const void* __restrict__ A, size_t aoff,
                                               const u16* __restrict__ BT,
                                               const void* __restrict__ b0p,
                                               const void* __restrict__ b1p,
                                               const void* __restrict__ b2p,
                                               void* __restrict__ C,
                                               int M, int N, int K,
                                               const int* __restrict__ dflag,
                                               int araw, int cf32) {
    const int fl = *dflag;
    const int af32 = araw && fl;
    const int z = blockIdx.z;
    const u16* Bz = BT + (size_t)z * N * K;
    const void* bias = (z == 0) ? b0p : (z == 1) ? b1p : b2p;

    __shared__ u16 As[128 * 32];
    __shared__ u16 Bs[128 * 32];

    const int tid  = threadIdx.x;
    const int lane = tid & 63;
    const int wave = tid >> 6;
    const int wm   = wave & 1;
    const int wn   = wave >> 1;
    const int quad = lane >> 4;
    const int l16  = lane & 15;

    const int m0 = blockIdx.y * 128;
    const int n0 = blockIdx.x * 128;

    f32x4 acc[4][4] = {};

    if (!af32) {
        // ---- async global_load_lds staging (m97 structure) ----
        const u16* Ab = (const u16*)A + aoff;
        int srow = wave * 32 + (lane >> 2);
        int scol = (lane & 3) * 8;
        int ar0 = m0 + srow;      if (ar0 > M - 1) ar0 = M - 1;
        int ar1 = m0 + srow + 16; if (ar1 > M - 1) ar1 = M - 1;
        const u16* gA0 = Ab + (size_t)ar0 * K + scol;
        const u16* gA1 = Ab + (size_t)ar1 * K + scol;
        const u16* gB0 = Bz + (size_t)(n0 + srow) * K + scol;
        const u16* gB1 = Bz + (size_t)(n0 + srow + 16) * K + scol;
        u16* lA0 = As + wave * 1024;
        u16* lA1 = As + wave * 1024 + 512;
        u16* lB0 = Bs + wave * 1024;
        u16* lB1 = Bs + wave * 1024 + 512;

        for (int k0 = 0; k0 < K; k0 += 32) {
            __syncthreads();
            gld16(gA0 + k0, lA0);
            gld16(gA1 + k0, lA1);
            gld16(gB0 + k0, lB0);
            gld16(gB1 + k0, lB1);
            __syncthreads();

            short8 af[4], bfr[4];
#pragma unroll
            for (int i = 0; i < 4; i++)
                af[i] = *(const short8*)(&As[(wm * 64 + i * 16 + l16) * 32 + quad * 8]);
#pragma unroll
            for (int j = 0; j < 4; j++)
                bfr[j] = *(const short8*)(&Bs[(wn * 64 + j * 16 + l16) * 32 + quad * 8]);
#pragma unroll
            for (int i = 0; i < 4; i++)
#pragma unroll
                for (int j = 0; j < 4; j++)
                    acc[i][j] = __builtin_amdgcn_mfma_f32_16x16x32_bf16(af[i], bfr[j], acc[i][j], 0, 0, 0);
        }
    } else {
        // ---- raw f32 A: VGPR pack path ----
        const int r0 = tid >> 2;
        const int kp = (tid & 3) << 3;
        int ga0 = m0 + r0;       if (ga0 > M - 1) ga0 = M - 1;
        int ga1 = m0 + r0 + 64;  if (ga1 > M - 1) ga1 = M - 1;
        const size_t arow0 = aoff + (size_t)ga0 * K + kp;
        const size_t arow1 = aoff + (size_t)ga1 * K + kp;
        const u16* Bp0 = Bz + (size_t)(n0 + r0) * K + kp;
        const u16* Bp1 = Bz + (size_t)(n0 + r0 + 64) * K + kp;

        for (int k0 = 0; k0 < K; k0 += 32) {
            short8 a0 = pack_f32x8((const float*)A + arow0 + k0);
            short8 a1 = pack_f32x8((const float*)A + arow1 + k0);
            short8 bv0 = *(const short8*)(Bp0 + k0);
            short8 bv1 = *(const short8*)(Bp1 + k0);
            __syncthreads();
            *(short8*)(&As[r0 * 32 + kp])        = a0;
            *(short8*)(&As[(r0 + 64) * 32 + kp]) = a1;
            *(short8*)(&Bs[r0 * 32 + kp])        = bv0;
            *(short8*)(&Bs[(r0 + 64) * 32 + kp]) = bv1;
            __syncthreads();

            short8 af[4], bfr[4];
#pragma unroll
            for (int i = 0; i < 4; i++)
                af[i] = *(const short8*)(&As[(wm * 64 + i * 16 + l16) * 32 + quad * 8]);
#pragma unroll
            for (int j = 0; j < 4; j++)
                bfr[j] = *(const short8*)(&Bs[(wn * 64 + j * 16 + l16) * 32 + quad * 8]);
#pragma unroll
            for (int i = 0; i < 4; i++)
#pragma unroll
                for (int j = 0; j < 4; j++)
                    acc[i][j] = __builtin_amdgcn_mfma_f32_16x16x32_bf16(af[i], bfr[j], acc[i][j], 0, 0, 0);
        }
    }

    // epilogue: D row = quad*4 + r (m), col = l16 (n)
#pragma unroll
    for (int j = 0; j < 4; j++) {
        int col = n0 + wn * 64 + j * 16 + l16;
        float bb = fl ? ((const float*)bias)[col] : b2f(((const u16*)bias)[col]);
#pragma unroll
        for (int i = 0; i < 4; i++) {
            int rowb = m0 + wm * 64 + i * 16 + quad * 4;
#pragma unroll
            for (int r = 0; r < 4; r++) {
                int row = rowb + r;
                if (row < M) {
                    size_t idx = (size_t)z * M * N + (size_t)row * N + col;
                    float v = acc[i][j][r] + bb;
                    if (cf32) ((float*)C)[idx] = v;
                    else      ((u16*)C)[idx]  = f2b(v);
                }
            }
        }
    }
}

// ------------------------- cls attention (split) ---------------------------
// grid (12, 32, bs): h, split, b_local.  P layout [z][bs*ROWS][N3], slab PZv.
__global__ __launch_bounds__(256) void cls_part(const u16* __restrict__ Pb, size_t PZv,
                                                float* __restrict__ part, int b0) {
    int h = blockIdx.x, sp = blockIdx.y, bl = blockIdx.z;
    int b = b0 + bl;
    int base = sp * CLS_RS;
    int cnt = ROWS - base; if (cnt > CLS_RS) cnt = CLS_RS;
    __shared__ float qs[192];
    __shared__ float sc[CLS_RS];
    __shared__ float red[4];
    int tid = threadIdx.x;
    const size_t hbase = (size_t)bl * ROWS * N3 + (size_t)h * 192;
    const u16* Pq  = Pb;            // z0
    const u16* Pkc = Pb + PZv;      // z1 (Wk) -> k_cls
    const u16* Pvc = Pb + 2 * PZv;  // z2 (Wv) -> v_cls

    if (tid < 192) qs[tid] = b2f(Pq[hbase + tid]);
    __syncthreads();

    float sval = -1e30f;
    if (tid < cnt) {
        const u16* kr = Pkc + hbase + (size_t)(base + tid) * N3;
        float s = 0.f;
        for (int d0 = 0; d0 < 192; d0 += 8) {
            short8 v8 = *(const short8*)(kr + d0);
#pragma unroll
            for (int j = 0; j < 8; j++) s += qs[d0 + j] * b2fs(v8[j]);
        }
        sval = s * SCALE;
    }
    float m = block_max256(sval, red);
    float e = (tid < cnt) ? __expf(sval - m) : 0.f;
    float l = block_sum256(e, red);
    if (tid < cnt) sc[tid] = e;
    __syncthreads();

    float* pp = part + ((size_t)(b * 12 + h) * CLS_NS + sp) * 194;
    if (tid == 0) { pp[0] = m; pp[1] = l; }
    if (tid < 192) {
        float acc = 0.f;
        const u16* vb = Pvc + hbase + tid;
        for (int r = 0; r < cnt; r++) acc += sc[r] * b2f(vb[(size_t)(base + r) * N3]);
        pp[2 + tid] = acc;
    }
}

__global__ __launch_bounds__(192) void cls_merge(const float* __restrict__ part,
                                                 u16* __restrict__ Fmat) {
    int h = blockIdx.x, b = blockIdx.y;
    int tid = threadIdx.x;
    const float* p0 = part + (size_t)(b * 12 + h) * CLS_NS * 194;
    float M = -1e30f;
#pragma unroll
    for (int s = 0; s < CLS_NS; s++) M = fmaxf(M, p0[s * 194]);
    float L = 0.f, acc = 0.f;
#pragma unroll
    for (int s = 0; s < CLS_NS; s++) {
        float w = __expf(p0[s * 194] - M);
        L += w * p0[s * 194 + 1];
        acc += w * p0[s * 194 + 2 + tid];
    }
    Fmat[(size_t)(b * 17) * N3 + (size_t)h * 192 + tid] = f2b(acc / L);
}

// --------------------------- temporal attention ----------------------------
// grid (195, 12, bs): p-1, h, b_local.
__global__ __launch_bounds__(128) void temporal_attn(const u16* __restrict__ Pb, size_t PZv,
                                                     const float* __restrict__ tab,
                                                     u16* __restrict__ tmp, int b0) {
    int p = blockIdx.x + 1, h = blockIdx.y, bl = blockIdx.z;
    int b = b0 + bl;
    __shared__ float Qs[16][192];
    __shared__ float Ks[16][192];
    __shared__ float Sm[16][17];
    __shared__ float w[16];
    int tid = threadIdx.x;
    const u16* Pq = Pb;            // z0 -> q
    const u16* Pk = Pb + 2 * PZv;  // z2 (Wv) -> k
    const u16* Pv = Pb + PZv;      // z1 (Wk) -> v
    const size_t rbase = (size_t)bl * ROWS;

    for (int t = tid; t < 3072; t += 128) {
        int mat = (t >= 1536);
        int i = mat ? t - 1536 : t;
        int f = i / 96;
        int d = (i % 96) * 2;
        int s = f * 196 + p;
        size_t idx = (rbase + 1 + s) * N3 + (size_t)h * 192 + d;
        const u16* src = mat ? Pk : Pq;
        float x1 = b2f(src[idx]), x2 = b2f(src[idx + 1]);
        if (d < 64) {
            const float* tp = tab + ((size_t)s * 32 + (d >> 1)) * 2;
            float cs = tp[0], sn = tp[1];
            float y1 = x1 * cs - x2 * sn;
            float y2 = x2 * cs + x1 * sn;
            x1 = y1; x2 = y2;
        }
        if (mat) { Ks[f][d] = x1; Ks[f][d + 1] = x2; }
        else     { Qs[f][d] = x1; Qs[f][d + 1] = x2; }
    }
    __syncthreads();

    for (int t = tid; t < 256; t += 128) {
        int f = t >> 4, g = t & 15;
        float s = 0.f;
#pragma unroll 8
        for (int d = 0; d < 192; d++) s += Qs[f][d] * Ks[g][d];
        Sm[f][g] = s * SCALE;
    }
    __syncthreads();
    if (tid < 16) {
        float m = -1e30f;
#pragma unroll
        for (int g = 0; g < 16; g++) m = fmaxf(m, Sm[tid][g]);
        float S = 0.f;
#pragma unroll
        for (int g = 0; g < 16; g++) { float e = __expf(Sm[tid][g] - m); Sm[tid][g] = e; S += e; }
        float inv = 1.0f / S;
#pragma unroll
        for (int g = 0; g < 16; g++) Sm[tid][g] *= inv;
    }
    __syncthreads();
    if (tid < 16) {
        float s = 0.f;
#pragma unroll
        for (int f = 0; f < 16; f++) s += Sm[f][tid];
        w[tid] = s;
    }
    __syncthreads();
    for (int d = tid; d < 192; d += 128) {
        float acc = 0.f;
#pragma unroll
        for (int g = 0; g < 16; g++) {
            size_t idx = (rbase + 1 + (size_t)g * 196 + p) * N3 + (size_t)h * 192 + d;
            acc += w[g] * b2f(Pv[idx]);
        }
        tmp[(size_t)(b * NPm1 + p - 1) * N3 + (size_t)h * 192 + d] = f2b(acc);
    }
}

// ------------------------- second attention scores -------------------------
// grid (13, 12, 8): qtile t, h, b.  Computes partial w for all 16 xi from
// LDS-staged K (195 rows) and Q (31 rows), accumulates into wacc via atomics.
__global__ __launch_bounds__(256) void wacc_zero(float* __restrict__ wacc) {
    wacc[blockIdx.x * 256 + threadIdx.x] = 0.f;   // grid sized exactly
}

__global__ __launch_bounds__(256) void attn2_sc(const u16* __restrict__ P2,
                                                float* __restrict__ wacc) {
    int t = blockIdx.x, h = blockIdx.y, b = blockIdx.z;
    __shared__ u16 Ks[195 * LDK];
    __shared__ u16 Qs[31 * LDK];
    __shared__ float pm[4][16], ps[4][16];
    int tid = threadIdx.x;
    const size_t hb = (size_t)b * NPm1 * N3 + (size_t)h * 192;
    const u16* Q  = P2;             // z0 -> q2
    const u16* Kc = P2 + 2 * P2Z;   // z2 (Wv) -> k2

    for (int i = tid; i < 195 * 24; i += 256) {
        int r = i / 24, c = (i % 24) * 8;
        *(short8*)&Ks[r * LDK + c] = *(const short8*)(Kc + hb + (size_t)r * N3 + c);
    }
    for (int i = tid; i < 31 * 24; i += 256) {
        int r = i / 24, c = (i % 24) * 8;
        int qr = (t * 16 + r) % 195;
        *(short8*)&Qs[r * LDK + c] = *(const short8*)(Q + hb + (size_t)qr * N3 + c);
    }
    __syncthreads();

    int wave = tid >> 6, lane = tid & 63, quad = lane >> 4, l16 = lane & 15;
    float* wb = wacc + (size_t)((b * 12 + h) * 16) * 196;

    // ---- xi >= 1 (16 keys each), wave-parallel ----
    for (int xi = 1 + wave; xi <= 15; xi += 4) {
        short8 Af[6], Bf[6];
#pragma unroll
        for (int ks = 0; ks < 6; ks++) {
            Af[ks] = *(const short8*)&Qs[(xi + l16) * LDK + quad * 8 + ks * 32];
            Bf[ks] = *(const short8*)&Ks[(xi + l16) * LDK + quad * 8 + ks * 32];
        }
        f32x4 S = {0.f, 0.f, 0.f, 0.f};
#pragma unroll
        for (int ks = 0; ks < 6; ks++)
            S = __builtin_amdgcn_mfma_f32_16x16x32_bf16(Af[ks], Bf[ks], S, 0, 0, 0);
        float wcol = 0.f;
#pragma unroll
        for (int r = 0; r < 4; r++) {
            float v = S[r] * SCALE;
            float m = v;
#pragma unroll
            for (int k = 1; k < 16; k <<= 1) m = fmaxf(m, __shfl_xor(m, k));
            float e = __expf(v - m);
            float l = e;
#pragma unroll
            for (int k = 1; k < 16; k <<= 1) l += __shfl_xor(l, k);
            bool qok = (t * 16 + quad * 4 + r) <= 195;
            wcol += qok ? e / l : 0.f;
        }
        wcol += __shfl_xor(wcol, 16);
        wcol += __shfl_xor(wcol, 32);
        if (quad == 0) atomicAdd(&wb[xi * 196 + l16], wcol);
    }

    // ---- xi == 0 (196 keys), chunks over waves, cross-wave softmax ----
    short8 Af0[6];
#pragma unroll
    for (int ks = 0; ks < 6; ks++)
        Af0[ks] = *(const short8*)&Qs[l16 * LDK + quad * 8 + ks * 32];

    f32x4 Sc[4];
    int   cl[4];
    int   cn = 0;
    for (int c = wave; c < 13; c += 4) {
        int g = c * 16 + l16;
        int krow = g % 195;
        short8 Bf[6];
#pragma unroll
        for (int ks = 0; ks < 6; ks++)
            Bf[ks] = *(const short8*)&Ks[krow * LDK + quad * 8 + ks * 32];
        f32x4 S = {0.f, 0.f, 0.f, 0.f};
#pragma unroll
        for (int ks = 0; ks < 6; ks++)
            S = __builtin_amdgcn_mfma_f32_16x16x32_bf16(Af0[ks], Bf[ks], S, 0, 0, 0);
        bool kbad = g > 195;
#pragma unroll
        for (int r = 0; r < 4; r++) S[r] = kbad ? -1e30f : S[r] * SCALE;
        Sc[cn] = S; cl[cn] = c; cn++;
    }
    // per-wave row max
#pragma unroll
    for (int r = 0; r < 4; r++) {
        float v = -1e30f;
        for (int n = 0; n < cn; n++) v = fmaxf(v, Sc[n][r]);
#pragma unroll
        for (int k = 1; k < 16; k <<= 1) v = fmaxf(v, __shfl_xor(v, k));
        if (l16 == 0) pm[wave][quad * 4 + r] = v;
    }
    __syncthreads();
    float gmx[4], tot[4];
#pragma unroll
    for (int r = 0; r < 4; r++) {
        int qr = quad * 4 + r;
        gmx[r] = fmaxf(fmaxf(pm[0][qr], pm[1][qr]), fmaxf(pm[2][qr], pm[3][qr]));
    }
    // exp + per-wave row sums
#pragma unroll
    for (int r = 0; r < 4; r++) {
        float s = 0.f;
        for (int n = 0; n < cn; n++) {
            float e = __expf(Sc[n][r] - gmx[r]);
            Sc[n][r] = e;
            s += e;
        }
#pragma unroll
        for (int k = 1; k < 16; k <<= 1) s += __shfl_xor(s, k);
        if (l16 == 0) ps[wave][quad * 4 + r] = s;
    }
    __syncthreads();
#pragma unroll
    for (int r = 0; r < 4; r++) {
        int qr = quad * 4 + r;
        tot[r] = (ps[0][qr] + ps[1][qr]) + (ps[2][qr] + ps[3][qr]);
    }
    for (int n = 0; n < cn; n++) {
        float wv = 0.f;
#pragma unroll
        for (int r = 0; r < 4; r++) {
            bool qok = (t * 16 + quad * 4 + r) <= 195;
            wv += qok ? Sc[n][r] / tot[r] : 0.f;
        }
        wv += __shfl_xor(wv, 16);
        wv += __shfl_xor(wv, 32);
        int g = cl[n] * 16 + l16;
        if (quad == 0 && g <= 195) atomicAdd(&wb[g], wv);
    }
}

// ---------------------------- attn2 epilogue -------------------------------
// grid (16, 12, 8): xi, h, b.  Fmat row = sum_g w[g] * V[krow(g)].
__global__ __launch_bounds__(192) void attn2_fin(const u16* __restrict__ P2,
                                                 const float* __restrict__ wacc,
                                                 u16* __restrict__ Fmat) {
    int xi = blockIdx.x, h = blockIdx.y, b = blockIdx.z;
    int Nk = (xi == 0) ? 196 : 16;
    int tid = threadIdx.x;
    const u16* V = P2 + P2Z;        // z1 (Wk) -> v2
    const size_t hb = (size_t)b * NPm1 * N3 + (size_t)h * 192;
    const float* wb = wacc + (size_t)((b * 12 + h) * 16 + xi) * 196;
    float acc = 0.f;
    for (int g = 0; g < Nk; g++) {
        int kr = (xi == 0) ? (g % 195) : (xi + g);
        acc += wb[g] * b2f(V[hb + (size_t)kr * N3 + tid]);
    }
    Fmat[(size_t)(b * 17 + 1 + xi) * N3 + (size_t)h * 192 + tid] = f2b(acc);
}

// ------------------------------ final scatter ------------------------------
__global__ __launch_bounds__(256) void scatter_out(const float* __restrict__ F17,
                                                   void* __restrict__ out,
                                                   const int* __restrict__ dflag) {
    const int fl = *dflag;
    int t = blockIdx.x * 256 + threadIdx.x;   // < 8*3137*96 exactly
    int c = t % 96;
    int rem = t / 96;
    int s = rem % ROWS;
    int b = rem / ROWS;
    int src = b * 17 + (s == 0 ? 0 : 1 + ((s - 1) & 15));
    const float* sp = F17 + ((size_t)src * 96 + c) * 8;
    if (fl) {
        float* o = (float*)out + (size_t)t * 8;
        *(float4*)o       = *(const float4*)sp;
        *(float4*)(o + 4) = *(const float4*)(sp + 4);
    } else {
        u16* o = (u16*)out + (size_t)t * 8;
        short8 v;
#pragma unroll
        for (int j = 0; j < 8; j++) v[j] = (short)f2b(sp[j]);
        *(short8*)o = v;
    }
}

// ------------------------------ host launcher ------------------------------
extern "C" void kernel_launch(void* const* d_in, const int* in_sizes, int n_in,
                              void* d_out, int out_size, void* d_ws, size_t ws_size,
                              hipStream_t stream) {
    const void* x   = d_in[0];
    const void* Wq  = d_in[1];
    const void* bq  = d_in[2];
    const void* Wk  = d_in[3];
    const void* bk  = d_in[4];
    const void* Wv  = d_in[5];
    const void* bv  = d_in[6];
    const void* Wt  = d_in[7];
    const void* bt  = d_in[8];
    const void* Wf  = d_in[9];
    const void* bfb = d_in[10];
    (void)in_sizes; (void)n_in; (void)out_size;

    auto al = [](size_t b) { return (b + 255) & ~(size_t)255; };
    const size_t szFlag = al(256);
    const size_t szWT   = al((size_t)3 * N3 * 768 * 2);
    const size_t szTmp  = al((size_t)MT * N3 * 2);
    const size_t szFmat = al((size_t)136 * N3 * 2);
    const size_t szRope = al((size_t)3136 * 32 * 2 * 4);
    const size_t szClsP = al((size_t)8 * 12 * CLS_NS * 194 * 4);
    const size_t szWacc = al((size_t)96 * 16 * 196 * 4);
    const size_t szXb   = al((size_t)8 * ROWS * 768 * 2);
    const size_t szB    = al(3 * P2Z * 2) + al((size_t)MT * 768 * 2) +
                          al((size_t)768 * N3 * 2) * 2 + al((size_t)136 * 768 * 4);
    const size_t basePerst = szFlag + szWT + szTmp + szFmat + szRope + szClsP + szWacc;

    int bs = 1; int usexb = 0;
    {
        const int cand[4] = {8, 4, 2, 1};
        for (int i = 0; i < 4; i++) {
            size_t szP = al((size_t)3 * cand[i] * ROWS * N3 * 2);
            size_t need = basePerst + szXb + (szP > szB ? szP : szB);
            if (ws_size >= need) { bs = cand[i]; usexb = 1; break; }
        }
        if (!usexb) {
            size_t szP = al((size_t)3 * ROWS * N3 * 2);
            size_t need = basePerst + (szP > szB ? szP : szB);
            if (ws_size < need) return;   // graceful mismatch instead of fault
        }
    }

    char* ws = (char*)d_ws;
    size_t off = 0;
    auto allocB = [&](size_t bytes) { char* p = ws + off; off += al(bytes); return p; };
    int*   dflag = (int*)allocB(256);
    u16*   WT    = (u16*)allocB((size_t)3 * N3 * 768 * 2);
    u16*   tmp   = (u16*)allocB((size_t)MT * N3 * 2);
    u16*   Fmat  = (u16*)allocB((size_t)136 * N3 * 2);
    float* ropeT = (float*)allocB((size_t)3136 * 32 * 2 * 4);
    float* clsP  = (float*)allocB((size_t)8 * 12 * CLS_NS * 194 * 4);
    float* wacc  = (float*)allocB((size_t)96 * 16 * 196 * 4);
    u16*   xb    = usexb ? (u16*)allocB((size_t)8 * ROWS * 768 * 2) : nullptr;
    size_t aliasOff = off;
    u16* Pb = (u16*)allocB((size_t)3 * bs * ROWS * N3 * 2);
    off = aliasOff;                                     // phase B aliases P
    u16*   P2  = (u16*)allocB(3 * P2Z * 2);
    u16*   tiu = (u16*)allocB((size_t)MT * 768 * 2);
    u16*   WtT = (u16*)allocB((size_t)768 * N3 * 2);
    u16*   WfT = (u16*)allocB((size_t)768 * N3 * 2);
    float* F17 = (float*)allocB((size_t)136 * 768 * 4);

    const size_t PZv = (size_t)bs * ROWS * N3;

    detect_dtype<<<dim3(1), 256, 0, stream>>>((const u16*)x, dflag);
    rope_tab_k<<<dim3(392), 256, 0, stream>>>(ropeT);
    if (usexb) convert_x<<<dim3(9411), 256, 0, stream>>>(x, xb, dflag);

    transpose_k<<<dim3(72, 24), 256, 0, stream>>>(Wq, WT, 768, N3, dflag);
    transpose_k<<<dim3(72, 24), 256, 0, stream>>>(Wk, WT + (size_t)N3 * 768, 768, N3, dflag);
    transpose_k<<<dim3(72, 24), 256, 0, stream>>>(Wv, WT + (size_t)2 * N3 * 768, 768, N3, dflag);

    // ---- phase A ----
    for (int b0 = 0; b0 < 8; b0 += bs) {
        int Mv = bs * ROWS;
        size_t aoff = (size_t)b0 * ROWS * 768;
        if (usexb)
            gemm_bt<<<dim3(18, (Mv + 127) / 128, 3), 256, 0, stream>>>(
                xb, aoff, WT, bq, bk, bv, Pb, Mv, N3, 768, dflag, 0, 0);
        else
            gemm_bt<<<dim3(18, (Mv + 127) / 128, 3), 256, 0, stream>>>(
                x, aoff, WT, bq, bk, bv, Pb, Mv, N3, 768, dflag, 1, 0);
        cls_part<<<dim3(12, CLS_NS, bs), 256, 0, stream>>>(Pb, PZv, clsP, b0);
        temporal_attn<<<dim3(195, 12, bs), 128, 0, stream>>>(Pb, PZv, ropeT, tmp, b0);
    }
    cls_merge<<<dim3(12, 8), 192, 0, stream>>>(clsP, Fmat);

    // ---- phase B ----
    transpose_k<<<dim3(24, 72), 256, 0, stream>>>(Wt, WtT, N3, 768, dflag);
    transpose_k<<<dim3(24, 72), 256, 0, stream>>>(Wf, WfT, N3, 768, dflag);

    gemm_bt<<<dim3(6, 13, 1), 256, 0, stream>>>(tmp, 0, WtT, bt, bt, bt, tiu,
                                                MT, 768, N3, dflag, 0, 0);
    gemm_bt<<<dim3(18, 13, 3), 256, 0, stream>>>(tiu, 0, WT, bq, bk, bv, P2,
                                                 MT, N3, 768, dflag, 0, 0);

    wacc_zero<<<dim3(1176), 256, 0, stream>>>(wacc);
    attn2_sc<<<dim3(13, 12, 8), 256, 0, stream>>>(P2, wacc);
    attn2_fin<<<dim3(16, 12, 8), 192, 0, stream>>>(P2, wacc, Fmat);

    gemm_bt<<<dim3(6, 2, 1), 256, 0, stream>>>(Fmat, 0, WfT, bfb, bfb, bfb, F17,
                                               136, 768, N3, dflag, 0, 1);

    scatter_out<<<dim3(9411), 256, 0, stream>>>(F17, d_out, dflag);
}

// Round 6
// 1180.461 us; speedup vs baseline: 7.8796x; 1.3636x over previous
//
#include <hip/hip_runtime.h>
#include <cstdint>
#include <cstddef>

// ---------------------------------------------------------------------------
// dividedSpaceTimeAttention — MI355X (gfx950), runtime-detected f32/bf16 I/O,
// bf16 intermediates, fp32 accumulate.
//
// R1: per-batch phase A + aliased phase B -> fits small workspace.
// R2: NaN root-caused to f32 inputs read as bf16 -> runtime dtype detection.
// R3: passed, 9.3 ms (attn2 serial f-loop = 4.45 ms).
// R4: attn2 MFMA-batched -> 2.08 ms; attn2 tail/occupancy bound.
// R5: attn2 tile-parallel LDS-staged; batched phase A; global_load_lds GEMM
//     -> 1.61 ms.  Stage-1 GEMM at ~830 TF (m97 plateau), 322 us.
// R6: temporal_attn -> short8 loads + vector rope + MFMA scores + LDS V;
//     cls_part -> coalesced LDS staging of K rows.  GEMM untouched.
// ---------------------------------------------------------------------------

typedef unsigned short u16;
typedef __attribute__((ext_vector_type(8))) short short8;   // 8 x bf16 raw
typedef __attribute__((ext_vector_type(4))) float f32x4;

#define DEV static __device__ __forceinline__
#define AS1 __attribute__((address_space(1)))
#define AS3 __attribute__((address_space(3)))

DEV float b2f(u16 u) { union { unsigned int i; float f; } v; v.i = ((unsigned int)u) << 16; return v.f; }
DEV float b2fs(short s) { return b2f((u16)s); }
DEV u16 f2b(float f) {
    union { float f; unsigned int i; } v; v.f = f;
    unsigned int r = v.i + 0x7fffu + ((v.i >> 16) & 1u);   // RNE
    return (u16)(r >> 16);
}
DEV void gld16(const u16* g, u16* l) {   // async global->LDS, 16 B/lane
    __builtin_amdgcn_global_load_lds((AS1 void*)(g), (AS3 void*)(l), 16, 0, 0);
}

constexpr int   ROWS  = 3137;               // SEQ+1
constexpr int   NPm1  = 195;
constexpr int   MT    = 8 * NPm1;           // 1560
constexpr int   N3    = 2304;               // NH*D3 == 3*DIM
constexpr float SCALE = 1.0f / 96.0f;       // 1/(sqrt(64)*12)
constexpr size_t P2Z  = (size_t)MT * N3;    // z-slab stride of P2
constexpr int   CLS_NS = 32;                // cls row splits
constexpr int   CLS_RS = 99;                // rows per split (32*99 >= 3137)
constexpr int   LDK   = 200;                // padded LDS row stride (u16)

// --------------------------- reductions (wave64) ---------------------------
DEV float wave_max(float v) {
#pragma unroll
    for (int off = 32; off; off >>= 1) v = fmaxf(v, __shfl_xor(v, off));
    return v;
}
DEV float wave_sum(float v) {
#pragma unroll
    for (int off = 32; off; off >>= 1) v += __shfl_xor(v, off);
    return v;
}
DEV float block_max256(float v, float* red) {
    v = wave_max(v);
    __syncthreads();
    if ((threadIdx.x & 63) == 0) red[threadIdx.x >> 6] = v;
    __syncthreads();
    return fmaxf(fmaxf(red[0], red[1]), fmaxf(red[2], red[3]));
}
DEV float block_sum256(float v, float* red) {
    v = wave_sum(v);
    __syncthreads();
    if ((threadIdx.x & 63) == 0) red[threadIdx.x >> 6] = v;
    __syncthreads();
    return (red[0] + red[1]) + (red[2] + red[3]);
}

// ----------------------------- dtype detection -----------------------------
__global__ __launch_bounds__(256) void detect_dtype(const u16* __restrict__ x,
                                                    int* __restrict__ flag) {
    __shared__ int cnt;
    if (threadIdx.x == 0) cnt = 0;
    __syncthreads();
    int c = 0;
    for (int i = threadIdx.x; i < 8192; i += 256) {
        unsigned e = (x[i] >> 7) & 0xFFu;
        if (e >= 134u) c++;
    }
#pragma unroll
    for (int off = 32; off; off >>= 1) c += __shfl_xor(c, off);
    if ((threadIdx.x & 63) == 0) atomicAdd(&cnt, c);
    __syncthreads();
    if (threadIdx.x == 0) *flag = (cnt > 16) ? 1 : 0;
}

// --------------------------- x -> bf16 pre-convert -------------------------
__global__ __launch_bounds__(256) void convert_x(const void* __restrict__ x,
                                                 u16* __restrict__ xb,
                                                 const int* __restrict__ dflag) {
    const int fl = *dflag;
    int t = blockIdx.x * 256 + threadIdx.x;       // < 2409216 exactly
    size_t e0 = (size_t)t * 8;
    if (fl) {
        const float* p = (const float*)x + e0;
        float4 u0 = *(const float4*)p, u1 = *(const float4*)(p + 4);
        short8 r;
        r[0]=(short)f2b(u0.x); r[1]=(short)f2b(u0.y); r[2]=(short)f2b(u0.z); r[3]=(short)f2b(u0.w);
        r[4]=(short)f2b(u1.x); r[5]=(short)f2b(u1.y); r[6]=(short)f2b(u1.z); r[7]=(short)f2b(u1.w);
        *(short8*)(xb + e0) = r;
    } else {
        *(short8*)(xb + e0) = *(const short8*)((const u16*)x + e0);
    }
}

// ------------------------------- transpose ---------------------------------
__global__ __launch_bounds__(256) void transpose_k(const void* __restrict__ in,
                                                   u16* __restrict__ out, int R, int C,
                                                   const int* __restrict__ dflag) {
    const int fl = *dflag;
    __shared__ u16 t[32][33];
    int bx = blockIdx.x * 32, by = blockIdx.y * 32;
    int tx = threadIdx.x & 31, ty = threadIdx.x >> 5;
#pragma unroll
    for (int i = 0; i < 32; i += 8) {
        int r = by + ty + i, c = bx + tx;
        if (r < R && c < C) {
            size_t idx = (size_t)r * C + c;
            t[ty + i][tx] = fl ? f2b(((const float*)in)[idx]) : ((const u16*)in)[idx];
        }
    }
    __syncthreads();
#pragma unroll
    for (int i = 0; i < 32; i += 8) {
        int c = bx + ty + i, r = by + tx;
        if (c < C && r < R) out[(size_t)c * R + r] = t[tx][ty + i];
    }
}

// ------------------------------ rope tables --------------------------------
__global__ __launch_bounds__(256) void rope_tab_k(float* __restrict__ tab) {
    int t = blockIdx.x * 256 + threadIdx.x;           // < 3136*32
    if (t >= 3136 * 32) return;
    int s = t >> 5, i = t & 31;
    float inv = powf(10000.0f, -(float)(2 * i) * (1.0f / 64.0f));
    float sn, cs;
    sincosf((float)s * inv, &sn, &cs);
    tab[t * 2]     = cs;
    tab[t * 2 + 1] = sn;
}

// --------------------------------- GEMM ------------------------------------
// C[z] = A(MxK) @ BT[z](NxK)^T + bias[z].  A bf16 (async LDS staging) unless
// araw&&fl (raw f32 -> pack path).  BT ws bf16.  bias raw.  C bf16 / f32.
DEV short8 pack_f32x8(const float* p) {
    const float4 u0 = *(const float4*)p;
    const float4 u1 = *(const float4*)(p + 4);
    short8 r;
    r[0]=(short)f2b(u0.x); r[1]=(short)f2b(u0.y); r[2]=(short)f2b(u0.z); r[3]=(short)f2b(u0.w);
    r[4]=(short)f2b(u1.x); r[5]=(short)f2b(u1.y); r[6]=(short)f2b(u1.z); r[7]=(short)f2b(u1.w);
    return r;
}

__global__ __launch_bounds__(256) void gemm_bt(const void* __restrict__ A, size_t aoff,
                                               const u16* __restrict__ BT,
                                               const void* __restrict__ b0p,
                                               const void* __restrict__ b1p,
                                               const void* __restrict__ b2p,
                                               void* __restrict__ C,
                                               int M, int N, int K,
                                               const int* __restrict__ dflag,
                                               int araw, int cf32) {
    const int fl = *dflag;
    const int af32 = araw && fl;
    const int z = blockIdx.z;
    const u16* Bz = BT + (size_t)z * N * K;
    const void* bias = (z == 0) ? b0p : (z == 1) ? b1p : b2p;

    __shared__ u16 As[128 * 32];
    __shared__ u16 Bs[128 * 32];

    const int tid  = threadIdx.x;
    const int lane = tid & 63;
    const int wave = tid >> 6;
    const int wm   = wave & 1;
    const int wn   = wave >> 1;
    const int quad = lane >> 4;
    const int l16  = lane & 15;

    const int m0 = blockIdx.y * 128;
    const int n0 = blockIdx.x * 128;

    f32x4 acc[4][4] = {};

    if (!af32) {
        const u16* Ab = (const u16*)A + aoff;
        int srow = wave * 32 + (lane >> 2);
        int scol = (lane & 3) * 8;
        int ar0 = m0 + srow;      if (ar0 > M - 1) ar0 = M - 1;
        int ar1 = m0 + srow + 16; if (ar1 > M - 1) ar1 = M - 1;
        const u16* gA0 = Ab + (size_t)ar0 * K + scol;
        const u16* gA1 = Ab + (size_t)ar1 * K + scol;
        const u16* gB0 = Bz + (size_t)(n0 + srow) * K + scol;
        const u16* gB1 = Bz + (size_t)(n0 + srow + 16) * K + scol;
        u16* lA0 = As + wave * 1024;
        u16* lA1 = As + wave * 1024 + 512;
        u16* lB0 = Bs + wave * 1024;
        u16* lB1 = Bs + wave * 1024 + 512;

        for (int k0 = 0; k0 < K; k0 += 32) {
            __syncthreads();
            gld16(gA0 + k0, lA0);
            gld16(gA1 + k0, lA1);
            gld16(gB0 + k0, lB0);
            gld16(gB1 + k0, lB1);
            __syncthreads();

            short8 af[4], bfr[4];
#pragma unroll
            for (int i = 0; i < 4; i++)
                af[i] = *(const short8*)(&As[(wm * 64 + i * 16 + l16) * 32 + quad * 8]);
#pragma unroll
            for (int j = 0; j < 4; j++)
                bfr[j] = *(const short8*)(&Bs[(wn * 64 + j * 16 + l16) * 32 + quad * 8]);
#pragma unroll
            for (int i = 0; i < 4; i++)
#pragma unroll
                for (int j = 0; j < 4; j++)
                    acc[i][j] = __builtin_amdgcn_mfma_f32_16x16x32_bf16(af[i], bfr[j], acc[i][j], 0, 0, 0);
        }
    } else {
        const int r0 = tid >> 2;
        const int kp = (tid & 3) << 3;
        int ga0 = m0 + r0;       if (ga0 > M - 1) ga0 = M - 1;
        int ga1 = m0 + r0 + 64;  if (ga1 > M - 1) ga1 = M - 1;
        const size_t arow0 = aoff + (size_t)ga0 * K + kp;
        const size_t arow1 = aoff + (size_t)ga1 * K + kp;
        const u16* Bp0 = Bz + (size_t)(n0 + r0) * K + kp;
        const u16* Bp1 = Bz + (size_t)(n0 + r0 + 64) * K + kp;

        for (int k0 = 0; k0 < K; k0 += 32) {
            short8 a0 = pack_f32x8((const float*)A + arow0 + k0);
            short8 a1 = pack_f32x8((const float*)A + arow1 + k0);
            short8 bv0 = *(const short8*)(Bp0 + k0);
            short8 bv1 = *(const short8*)(Bp1 + k0);
            __syncthreads();
            *(short8*)(&As[r0 * 32 + kp])        = a0;
            *(short8*)(&As[(r0 + 64) * 32 + kp]) = a1;
            *(short8*)(&Bs[r0 * 32 + kp])        = bv0;
            *(short8*)(&Bs[(r0 + 64) * 32 + kp]) = bv1;
            __syncthreads();

            short8 af[4], bfr[4];
#pragma unroll
            for (int i = 0; i < 4; i++)
                af[i] = *(const short8*)(&As[(wm * 64 + i * 16 + l16) * 32 + quad * 8]);
#pragma unroll
            for (int j = 0; j < 4; j++)
                bfr[j] = *(const short8*)(&Bs[(wn * 64 + j * 16 + l16) * 32 + quad * 8]);
#pragma unroll
            for (int i = 0; i < 4; i++)
#pragma unroll
                for (int j = 0; j < 4; j++)
                    acc[i][j] = __builtin_amdgcn_mfma_f32_16x16x32_bf16(af[i], bfr[j], acc[i][j], 0, 0, 0);
        }
    }

    // epilogue: D row = quad*4 + r (m), col = l16 (n)
#pragma unroll
    for (int j = 0; j < 4; j++) {
        int col = n0 + wn * 64 + j * 16 + l16;
        float bb = fl ? ((const float*)bias)[col] : b2f(((const u16*)bias)[col]);
#pragma unroll
        for (int i = 0; i < 4; i++) {
            int rowb = m0 + wm * 64 + i * 16 + quad * 4;
#pragma unroll
            for (int r = 0; r < 4; r++) {
                int row = rowb + r;
                if (row < M) {
                    size_t idx = (size_t)z * M * N + (size_t)row * N + col;
                    float v = acc[i][j][r] + bb;
                    if (cf32) ((float*)C)[idx] = v;
                    else      ((u16*)C)[idx]  = f2b(v);
                }
            }
        }
    }
}

// ------------------------- cls attention (split) ---------------------------
// grid (12, 32, bs): h, split, b_local.  K rows staged via coalesced LDS.
__global__ __launch_bounds__(256) void cls_part(const u16* __restrict__ Pb, size_t PZv,
                                                float* __restrict__ part, int b0) {
    int h = blockIdx.x, sp = blockIdx.y, bl = blockIdx.z;
    int b = b0 + bl;
    int base = sp * CLS_RS;
    int cnt = ROWS - base; if (cnt > CLS_RS) cnt = CLS_RS;
    __shared__ u16 Ksh[CLS_RS * LDK];       // 39.6 KB
    __shared__ float qs[192];
    __shared__ float sc[CLS_RS];
    __shared__ float red[4];
    int tid = threadIdx.x;
    const size_t hbase = (size_t)bl * ROWS * N3 + (size_t)h * 192;
    const u16* Pq  = Pb;            // z0
    const u16* Pkc = Pb + PZv;      // z1 (Wk) -> k_cls
    const u16* Pvc = Pb + 2 * PZv;  // z2 (Wv) -> v_cls

    if (tid < 192) qs[tid] = b2f(Pq[hbase + tid]);
    for (int i = tid; i < cnt * 24; i += 256) {
        int r = i / 24, c = (i % 24) * 8;
        *(short8*)&Ksh[r * LDK + c] =
            *(const short8*)(Pkc + hbase + (size_t)(base + r) * N3 + c);
    }
    __syncthreads();

    float sval = -1e30f;
    if (tid < cnt) {
        float s = 0.f;
#pragma unroll
        for (int c = 0; c < 24; c++) {
            short8 v8 = *(const short8*)&Ksh[tid * LDK + c * 8];
#pragma unroll
            for (int j = 0; j < 8; j++) s += qs[c * 8 + j] * b2fs(v8[j]);
        }
        sval = s * SCALE;
    }
    float m = block_max256(sval, red);
    float e = (tid < cnt) ? __expf(sval - m) : 0.f;
    float l = block_sum256(e, red);
    if (tid < cnt) sc[tid] = e;
    __syncthreads();

    float* pp = part + ((size_t)(b * 12 + h) * CLS_NS + sp) * 194;
    if (tid == 0) { pp[0] = m; pp[1] = l; }
    if (tid < 192) {
        float acc = 0.f;
        const u16* vb = Pvc + hbase + tid;
        for (int r = 0; r < cnt; r++) acc += sc[r] * b2f(vb[(size_t)(base + r) * N3]);
        pp[2 + tid] = acc;
    }
}

__global__ __launch_bounds__(192) void cls_merge(const float* __restrict__ part,
                                                 u16* __restrict__ Fmat) {
    int h = blockIdx.x, b = blockIdx.y;
    int tid = threadIdx.x;
    const float* p0 = part + (size_t)(b * 12 + h) * CLS_NS * 194;
    float M = -1e30f;
#pragma unroll
    for (int s = 0; s < CLS_NS; s++) M = fmaxf(M, p0[s * 194]);
    float L = 0.f, acc = 0.f;
#pragma unroll
    for (int s = 0; s < CLS_NS; s++) {
        float w = __expf(p0[s * 194] - M);
        L += w * p0[s * 194 + 1];
        acc += w * p0[s * 194 + 2 + tid];
    }
    Fmat[(size_t)(b * 17) * N3 + (size_t)h * 192 + tid] = f2b(acc / L);
}

// --------------------------- temporal attention ----------------------------
// grid (195, 12, bs): p-1, h, b_local.  short8 loads + vector rope; MFMA
// scores on wave 0 (register softmax); V applied from LDS.
__global__ __launch_bounds__(128) void temporal_attn(const u16* __restrict__ Pb, size_t PZv,
                                                     const float* __restrict__ tab,
                                                     u16* __restrict__ tmp, int b0) {
    int p = blockIdx.x + 1, h = blockIdx.y, bl = blockIdx.z;
    int b = b0 + bl;
    __shared__ u16 Qs[16 * LDK];
    __shared__ u16 Ks[16 * LDK];
    __shared__ u16 Vs[16 * LDK];
    __shared__ float w[16];
    int tid = threadIdx.x;
    const u16* Pq = Pb;            // z0 -> q
    const u16* Pk = Pb + 2 * PZv;  // z2 (Wv) -> k
    const u16* Pv = Pb + PZv;      // z1 (Wk) -> v
    const size_t rbase = (size_t)bl * ROWS;

    for (int i = tid; i < 384; i += 128) {
        int f = i / 24, c = (i % 24) * 8;
        int s = f * 196 + p;
        size_t gidx = (rbase + 1 + s) * N3 + (size_t)h * 192 + c;
        short8 q8 = *(const short8*)(Pq + gidx);
        short8 k8 = *(const short8*)(Pk + gidx);
        short8 v8 = *(const short8*)(Pv + gidx);
        if (c < 64) {
            const float* tp = tab + ((size_t)s * 32 + (c >> 1)) * 2;
            float4 t0 = *(const float4*)tp;        // cos0 sin0 cos1 sin1
            float4 t1 = *(const float4*)(tp + 4);  // cos2 sin2 cos3 sin3
            float cs[4] = {t0.x, t0.z, t1.x, t1.z};
            float sn[4] = {t0.y, t0.w, t1.y, t1.w};
            short8 qo, ko;
#pragma unroll
            for (int j = 0; j < 4; j++) {
                float q1 = b2fs(q8[2 * j]), q2 = b2fs(q8[2 * j + 1]);
                float k1 = b2fs(k8[2 * j]), k2 = b2fs(k8[2 * j + 1]);
                qo[2 * j]     = (short)f2b(q1 * cs[j] - q2 * sn[j]);
                qo[2 * j + 1] = (short)f2b(q2 * cs[j] + q1 * sn[j]);
                ko[2 * j]     = (short)f2b(k1 * cs[j] - k2 * sn[j]);
                ko[2 * j + 1] = (short)f2b(k2 * cs[j] + k1 * sn[j]);
            }
            q8 = qo; k8 = ko;
        }
        *(short8*)&Qs[f * LDK + c] = q8;
        *(short8*)&Ks[f * LDK + c] = k8;
        *(short8*)&Vs[f * LDK + c] = v8;
    }
    __syncthreads();

    if (tid < 64) {   // wave 0: MFMA scores + softmax + column sums
        int quad = tid >> 4, l16 = tid & 15;
        short8 Af[6], Bf[6];
#pragma unroll
        for (int ks = 0; ks < 6; ks++) {
            Af[ks] = *(const short8*)&Qs[l16 * LDK + quad * 8 + ks * 32];
            Bf[ks] = *(const short8*)&Ks[l16 * LDK + quad * 8 + ks * 32];
        }
        f32x4 S = {0.f, 0.f, 0.f, 0.f};
#pragma unroll
        for (int ks = 0; ks < 6; ks++)
            S = __builtin_amdgcn_mfma_f32_16x16x32_bf16(Af[ks], Bf[ks], S, 0, 0, 0);
        float wcol = 0.f;
#pragma unroll
        for (int r = 0; r < 4; r++) {
            float v = S[r] * SCALE;       // row = query frame quad*4+r, col = key l16
            float m = v;
#pragma unroll
            for (int k = 1; k < 16; k <<= 1) m = fmaxf(m, __shfl_xor(m, k));
            float e = __expf(v - m);
            float l = e;
#pragma unroll
            for (int k = 1; k < 16; k <<= 1) l += __shfl_xor(l, k);
            wcol += e / l;
        }
        wcol += __shfl_xor(wcol, 16);
        wcol += __shfl_xor(wcol, 32);
        if (quad == 0) w[l16] = wcol;
    }
    __syncthreads();

    for (int d = tid; d < 192; d += 128) {
        float acc = 0.f;
#pragma unroll
        for (int g = 0; g < 16; g++) acc += w[g] * b2f(Vs[g * LDK + d]);
        tmp[(size_t)(b * NPm1 + p - 1) * N3 + (size_t)h * 192 + d] = f2b(acc);
    }
}

// ------------------------- second attention scores -------------------------
__global__ __launch_bounds__(256) void wacc_zero(float* __restrict__ wacc) {
    wacc[blockIdx.x * 256 + threadIdx.x] = 0.f;   // grid sized exactly
}

__global__ __launch_bounds__(256) void attn2_sc(const u16* __restrict__ P2,
                                                float* __restrict__ wacc) {
    int t = blockIdx.x, h = blockIdx.y, b = blockIdx.z;
    __shared__ u16 Ks[195 * LDK];
    __shared__ u16 Qs[31 * LDK];
    __shared__ float pm[4][16], ps[4][16];
    int tid = threadIdx.x;
    const size_t hb = (size_t)b * NPm1 * N3 + (size_t)h * 192;
    const u16* Q  = P2;             // z0 -> q2
    const u16* Kc = P2 + 2 * P2Z;   // z2 (Wv) -> k2

    for (int i = tid; i < 195 * 24; i += 256) {
        int r = i / 24, c = (i % 24) * 8;
        *(short8*)&Ks[r * LDK + c] = *(const short8*)(Kc + hb + (size_t)r * N3 + c);
    }
    for (int i = tid; i < 31 * 24; i += 256) {
        int r = i / 24, c = (i % 24) * 8;
        int qr = (t * 16 + r) % 195;
        *(short8*)&Qs[r * LDK + c] = *(const short8*)(Q + hb + (size_t)qr * N3 + c);
    }
    __syncthreads();

    int wave = tid >> 6, lane = tid & 63, quad = lane >> 4, l16 = lane & 15;
    float* wb = wacc + (size_t)((b * 12 + h) * 16) * 196;

    // ---- xi >= 1 (16 keys each), wave-parallel ----
    for (int xi = 1 + wave; xi <= 15; xi += 4) {
        short8 Af[6], Bf[6];
#pragma unroll
        for (int ks = 0; ks < 6; ks++) {
            Af[ks] = *(const short8*)&Qs[(xi + l16) * LDK + quad * 8 + ks * 32];
            Bf[ks] = *(const short8*)&Ks[(xi + l16) * LDK + quad * 8 + ks * 32];
        }
        f32x4 S = {0.f, 0.f, 0.f, 0.f};
#pragma unroll
        for (int ks = 0; ks < 6; ks++)
            S = __builtin_amdgcn_mfma_f32_16x16x32_bf16(Af[ks], Bf[ks], S, 0, 0, 0);
        float wcol = 0.f;
#pragma unroll
        for (int r = 0; r < 4; r++) {
            float v = S[r] * SCALE;
            float m = v;
#pragma unroll
            for (int k = 1; k < 16; k <<= 1) m = fmaxf(m, __shfl_xor(m, k));
            float e = __expf(v - m);
            float l = e;
#pragma unroll
            for (int k = 1; k < 16; k <<= 1) l += __shfl_xor(l, k);
            bool qok = (t * 16 + quad * 4 + r) <= 195;
            wcol += qok ? e / l : 0.f;
        }
        wcol += __shfl_xor(wcol, 16);
        wcol += __shfl_xor(wcol, 32);
        if (quad == 0) atomicAdd(&wb[xi * 196 + l16], wcol);
    }

    // ---- xi == 0 (196 keys), chunks over waves, cross-wave softmax ----
    short8 Af0[6];
#pragma unroll
    for (int ks = 0; ks < 6; ks++)
        Af0[ks] = *(const short8*)&Qs[l16 * LDK + quad * 8 + ks * 32];

    f32x4 Sc[4];
    int   cl[4];
    int   cn = 0;
    for (int c = wave; c < 13; c += 4) {
        int g = c * 16 + l16;
        int krow = g % 195;
        short8 Bf[6];
#pragma unroll
        for (int ks = 0; ks < 6; ks++)
            Bf[ks] = *(const short8*)&Ks[krow * LDK + quad * 8 + ks * 32];
        f32x4 S = {0.f, 0.f, 0.f, 0.f};
#pragma unroll
        for (int ks = 0; ks < 6; ks++)
            S = __builtin_amdgcn_mfma_f32_16x16x32_bf16(Af0[ks], Bf[ks], S, 0, 0, 0);
        bool kbad = g > 195;
#pragma unroll
        for (int r = 0; r < 4; r++) S[r] = kbad ? -1e30f : S[r] * SCALE;
        Sc[cn] = S; cl[cn] = c; cn++;
    }
#pragma unroll
    for (int r = 0; r < 4; r++) {
        float v = -1e30f;
        for (int n = 0; n < cn; n++) v = fmaxf(v, Sc[n][r]);
#pragma unroll
        for (int k = 1; k < 16; k <<= 1) v = fmaxf(v, __shfl_xor(v, k));
        if (l16 == 0) pm[wave][quad * 4 + r] = v;
    }
    __syncthreads();
    float gmx[4], tot[4];
#pragma unroll
    for (int r = 0; r < 4; r++) {
        int qr = quad * 4 + r;
        gmx[r] = fmaxf(fmaxf(pm[0][qr], pm[1][qr]), fmaxf(pm[2][qr], pm[3][qr]));
    }
#pragma unroll
    for (int r = 0; r < 4; r++) {
        float s = 0.f;
        for (int n = 0; n < cn; n++) {
            float e = __expf(Sc[n][r] - gmx[r]);
            Sc[n][r] = e;
            s += e;
        }
#pragma unroll
        for (int k = 1; k < 16; k <<= 1) s += __shfl_xor(s, k);
        if (l16 == 0) ps[wave][quad * 4 + r] = s;
    }
    __syncthreads();
#pragma unroll
    for (int r = 0; r < 4; r++) {
        int qr = quad * 4 + r;
        tot[r] = (ps[0][qr] + ps[1][qr]) + (ps[2][qr] + ps[3][qr]);
    }
    for (int n = 0; n < cn; n++) {
        float wv = 0.f;
#pragma unroll
        for (int r = 0; r < 4; r++) {
            bool qok = (t * 16 + quad * 4 + r) <= 195;
            wv += qok ? Sc[n][r] / tot[r] : 0.f;
        }
        wv += __shfl_xor(wv, 16);
        wv += __shfl_xor(wv, 32);
        int g = cl[n] * 16 + l16;
        if (quad == 0 && g <= 195) atomicAdd(&wb[g], wv);
    }
}

// ---------------------------- attn2 epilogue -------------------------------
__global__ __launch_bounds__(192) void attn2_fin(const u16* __restrict__ P2,
                                                 const float* __restrict__ wacc,
                                                 u16* __restrict__ Fmat) {
    int xi = blockIdx.x, h = blockIdx.y, b = blockIdx.z;
    int Nk = (xi == 0) ? 196 : 16;
    int tid = threadIdx.x;
    const u16* V = P2 + P2Z;        // z1 (Wk) -> v2
    const size_t hb = (size_t)b * NPm1 * N3 + (size_t)h * 192;
    const float* wb = wacc + (size_t)((b * 12 + h) * 16 + xi) * 196;
    float acc = 0.f;
    for (int g = 0; g < Nk; g++) {
        int kr = (xi == 0) ? (g % 195) : (xi + g);
        acc += wb[g] * b2f(V[hb + (size_t)kr * N3 + tid]);
    }
    Fmat[(size_t)(b * 17 + 1 + xi) * N3 + (size_t)h * 192 + tid] = f2b(acc);
}

// ------------------------------ final scatter ------------------------------
__global__ __launch_bounds__(256) void scatter_out(const float* __restrict__ F17,
                                                   void* __restrict__ out,
                                                   const int* __restrict__ dflag) {
    const int fl = *dflag;
    int t = blockIdx.x * 256 + threadIdx.x;   // < 8*3137*96 exactly
    int c = t % 96;
    int rem = t / 96;
    int s = rem % ROWS;
    int b = rem / ROWS;
    int src = b * 17 + (s == 0 ? 0 : 1 + ((s - 1) & 15));
    const float* sp = F17 + ((size_t)src * 96 + c) * 8;
    if (fl) {
        float* o = (float*)out + (size_t)t * 8;
        *(float4*)o       = *(const float4*)sp;
        *(float4*)(o + 4) = *(const float4*)(sp + 4);
    } else {
        u16* o = (u16*)out + (size_t)t * 8;
        short8 v;
#pragma unroll
        for (int j = 0; j < 8; j++) v[j] = (short)f2b(sp[j]);
        *(short8*)o = v;
    }
}

// ------------------------------ host launcher ------------------------------
extern "C" void kernel_launch(void* const* d_in, const int* in_sizes, int n_in,
                              void* d_out, int out_size, void* d_ws, size_t ws_size,
                              hipStream_t stream) {
    const void* x   = d_in[0];
    const void* Wq  = d_in[1];
    const void* bq  = d_in[2];
    const void* Wk  = d_in[3];
    const void* bk  = d_in[4];
    const void* Wv  = d_in[5];
    const void* bv  = d_in[6];
    const void* Wt  = d_in[7];
    const void* bt  = d_in[8];
    const void* Wf  = d_in[9];
    const void* bfb = d_in[10];
    (void)in_sizes; (void)n_in; (void)out_size;

    auto al = [](size_t b) { return (b + 255) & ~(size_t)255; };
    const size_t szFlag = al(256);
    const size_t szWT   = al((size_t)3 * N3 * 768 * 2);
    const size_t szTmp  = al((size_t)MT * N3 * 2);
    const size_t szFmat = al((size_t)136 * N3 * 2);
    const size_t szRope = al((size_t)3136 * 32 * 2 * 4);
    const size_t szClsP = al((size_t)8 * 12 * CLS_NS * 194 * 4);
    const size_t szWacc = al((size_t)96 * 16 * 196 * 4);
    const size_t szXb   = al((size_t)8 * ROWS * 768 * 2);
    const size_t szB    = al(3 * P2Z * 2) + al((size_t)MT * 768 * 2) +
                          al((size_t)768 * N3 * 2) * 2 + al((size_t)136 * 768 * 4);
    const size_t basePerst = szFlag + szWT + szTmp + szFmat + szRope + szClsP + szWacc;

    int bs = 1; int usexb = 0;
    {
        const int cand[4] = {8, 4, 2, 1};
        for (int i = 0; i < 4; i++) {
            size_t szP = al((size_t)3 * cand[i] * ROWS * N3 * 2);
            size_t need = basePerst + szXb + (szP > szB ? szP : szB);
            if (ws_size >= need) { bs = cand[i]; usexb = 1; break; }
        }
        if (!usexb) {
            size_t szP = al((size_t)3 * ROWS * N3 * 2);
            size_t need = basePerst + (szP > szB ? szP : szB);
            if (ws_size < need) return;   // graceful mismatch instead of fault
        }
    }

    char* ws = (char*)d_ws;
    size_t off = 0;
    auto allocB = [&](size_t bytes) { char* p = ws + off; off += al(bytes); return p; };
    int*   dflag = (int*)allocB(256);
    u16*   WT    = (u16*)allocB((size_t)3 * N3 * 768 * 2);
    u16*   tmp   = (u16*)allocB((size_t)MT * N3 * 2);
    u16*   Fmat  = (u16*)allocB((size_t)136 * N3 * 2);
    float* ropeT = (float*)allocB((size_t)3136 * 32 * 2 * 4);
    float* clsP  = (float*)allocB((size_t)8 * 12 * CLS_NS * 194 * 4);
    float* wacc  = (float*)allocB((size_t)96 * 16 * 196 * 4);
    u16*   xb    = usexb ? (u16*)allocB((size_t)8 * ROWS * 768 * 2) : nullptr;
    size_t aliasOff = off;
    u16* Pb = (u16*)allocB((size_t)3 * bs * ROWS * N3 * 2);
    off = aliasOff;                                     // phase B aliases P
    u16*   P2  = (u16*)allocB(3 * P2Z * 2);
    u16*   tiu = (u16*)allocB((size_t)MT * 768 * 2);
    u16*   WtT = (u16*)allocB((size_t)768 * N3 * 2);
    u16*   WfT = (u16*)allocB((size_t)768 * N3 * 2);
    float* F17 = (float*)allocB((size_t)136 * 768 * 4);

    const size_t PZv = (size_t)bs * ROWS * N3;

    detect_dtype<<<dim3(1), 256, 0, stream>>>((const u16*)x, dflag);
    rope_tab_k<<<dim3(392), 256, 0, stream>>>(ropeT);
    if (usexb) convert_x<<<dim3(9411), 256, 0, stream>>>(x, xb, dflag);

    transpose_k<<<dim3(72, 24), 256, 0, stream>>>(Wq, WT, 768, N3, dflag);
    transpose_k<<<dim3(72, 24), 256, 0, stream>>>(Wk, WT + (size_t)N3 * 768, 768, N3, dflag);
    transpose_k<<<dim3(72, 24), 256, 0, stream>>>(Wv, WT + (size_t)2 * N3 * 768, 768, N3, dflag);

    // ---- phase A ----
    for (int b0 = 0; b0 < 8; b0 += bs) {
        int Mv = bs * ROWS;
        size_t aoff = (size_t)b0 * ROWS * 768;
        if (usexb)
            gemm_bt<<<dim3(18, (Mv + 127) / 128, 3), 256, 0, stream>>>(
                xb, aoff, WT, bq, bk, bv, Pb, Mv, N3, 768, dflag, 0, 0);
        else
            gemm_bt<<<dim3(18, (Mv + 127) / 128, 3), 256, 0, stream>>>(
                x, aoff, WT, bq, bk, bv, Pb, Mv, N3, 768, dflag, 1, 0);
        cls_part<<<dim3(12, CLS_NS, bs), 256, 0, stream>>>(Pb, PZv, clsP, b0);
        temporal_attn<<<dim3(195, 12, bs), 128, 0, stream>>>(Pb, PZv, ropeT, tmp, b0);
    }
    cls_merge<<<dim3(12, 8), 192, 0, stream>>>(clsP, Fmat);

    // ---- phase B ----
    transpose_k<<<dim3(24, 72), 256, 0, stream>>>(Wt, WtT, N3, 768, dflag);
    transpose_k<<<dim3(24, 72), 256, 0, stream>>>(Wf, WfT, N3, 768, dflag);

    gemm_bt<<<dim3(6, 13, 1), 256, 0, stream>>>(tmp, 0, WtT, bt, bt, bt, tiu,
                                                MT, 768, N3, dflag, 0, 0);
    gemm_bt<<<dim3(18, 13, 3), 256, 0, stream>>>(tiu, 0, WT, bq, bk, bv, P2,
                                                 MT, N3, 768, dflag, 0, 0);

    wacc_zero<<<dim3(1176), 256, 0, stream>>>(wacc);
    attn2_sc<<<dim3(13, 12, 8), 256, 0, stream>>>(P2, wacc);
    attn2_fin<<<dim3(16, 12, 8), 192, 0, stream>>>(P2, wacc, Fmat);

    gemm_bt<<<dim3(6, 2, 1), 256, 0, stream>>>(Fmat, 0, WfT, bfb, bfb, bfb, F17,
                                               136, 768, N3, dflag, 0, 1);

    scatter_out<<<dim3(9411), 256, 0, stream>>>(F17, d_out, dflag);
}

// Round 7
// 1163.329 us; speedup vs baseline: 7.9957x; 1.0147x over previous
//
#include <hip/hip_runtime.h>
#include <cstdint>
#include <cstddef>

// ---------------------------------------------------------------------------
// dividedSpaceTimeAttention — MI355X (gfx950), runtime-detected f32/bf16 I/O,
// bf16 intermediates, fp32 accumulate.
//
// R3: 9.3 ms -> R4: 2.08 ms -> R5: 1.61 ms -> R6: 1.18 ms.
// R6 counters: stage-1 GEMM 300 us (m97 plateau ~890 TF); ~550 us of the
//   remaining time unattributed by per-kernel models -> dispatch-gap theory.
// R7: 19 dispatches -> 9.  prep fuses transposes+convert+zero+rope; inline
//   per-block dtype probe removes the dflag dependency; cls+temporal fused;
//   merge+fin fused.  GEMM untouched.
// ---------------------------------------------------------------------------

typedef unsigned short u16;
typedef __attribute__((ext_vector_type(8))) short short8;   // 8 x bf16 raw
typedef __attribute__((ext_vector_type(4))) float f32x4;

#define DEV static __device__ __forceinline__
#define AS1 __attribute__((address_space(1)))
#define AS3 __attribute__((address_space(3)))

DEV float b2f(u16 u) { union { unsigned int i; float f; } v; v.i = ((unsigned int)u) << 16; return v.f; }
DEV float b2fs(short s) { return b2f((u16)s); }
DEV u16 f2b(float f) {
    union { float f; unsigned int i; } v; v.f = f;
    unsigned int r = v.i + 0x7fffu + ((v.i >> 16) & 1u);   // RNE
    return (u16)(r >> 16);
}
DEV void gld16(const u16* g, u16* l) {   // async global->LDS, 16 B/lane
    __builtin_amdgcn_global_load_lds((AS1 void*)(g), (AS3 void*)(l), 16, 0, 0);
}

// Wave-uniform inline dtype probe: x[0:512] low half-words.  f32 data -> ~120
// "impossible bf16" exponents (>=134, |v|>=128); bf16 N(0,1) data -> 0.
DEV int detect_fl(const u16* x) {
    int lane = threadIdx.x & 63;
    const u16* p = x + lane * 8;
    int c = 0;
#pragma unroll
    for (int j = 0; j < 8; j++) c += (((p[j] >> 7) & 0xFFu) >= 134u);
#pragma unroll
    for (int off = 32; off; off >>= 1) c += __shfl_xor(c, off);
    return c > 8;
}

constexpr int   ROWS  = 3137;               // SEQ+1
constexpr int   NPm1  = 195;
constexpr int   MT    = 8 * NPm1;           // 1560
constexpr int   N3    = 2304;               // NH*D3 == 3*DIM
constexpr float SCALE = 1.0f / 96.0f;       // 1/(sqrt(64)*12)
constexpr size_t P2Z  = (size_t)MT * N3;    // z-slab stride of P2
constexpr int   CLS_NS = 32;                // cls row splits
constexpr int   CLS_RS = 99;                // rows per split (32*99 >= 3137)
constexpr int   LDK   = 200;                // padded LDS row stride (u16)

// --------------------------- reductions (wave64) ---------------------------
DEV float wave_max(float v) {
#pragma unroll
    for (int off = 32; off; off >>= 1) v = fmaxf(v, __shfl_xor(v, off));
    return v;
}
DEV float wave_sum(float v) {
#pragma unroll
    for (int off = 32; off; off >>= 1) v += __shfl_xor(v, off);
    return v;
}
DEV float block_max256(float v, float* red) {
    v = wave_max(v);
    __syncthreads();
    if ((threadIdx.x & 63) == 0) red[threadIdx.x >> 6] = v;
    __syncthreads();
    return fmaxf(fmaxf(red[0], red[1]), fmaxf(red[2], red[3]));
}
DEV float block_sum256(float v, float* red) {
    v = wave_sum(v);
    __syncthreads();
    if ((threadIdx.x & 63) == 0) red[threadIdx.x >> 6] = v;
    __syncthreads();
    return (red[0] + red[1]) + (red[2] + red[3]);
}

// --------------------------------- prep ------------------------------------
// Fused: 5 weight transposes + x->bf16 convert + wacc zero + rope table.
DEV void do_transpose(const void* in, u16* out, int R, int C,
                      int bx, int by, int fl, u16 (*tls)[33]) {
    int tx = threadIdx.x & 31, ty = threadIdx.x >> 5;
#pragma unroll
    for (int i = 0; i < 32; i += 8) {
        int r = by + ty + i, c = bx + tx;
        size_t idx = (size_t)r * C + c;
        tls[ty + i][tx] = fl ? f2b(((const float*)in)[idx]) : ((const u16*)in)[idx];
    }
    __syncthreads();
#pragma unroll
    for (int i = 0; i < 32; i += 8) {
        int c = bx + ty + i, r = by + tx;
        out[(size_t)c * R + r] = tls[tx][ty + i];
    }
}

__global__ __launch_bounds__(256) void prep(const u16* __restrict__ x,
                                            const void* __restrict__ Wq,
                                            const void* __restrict__ Wk,
                                            const void* __restrict__ Wv,
                                            const void* __restrict__ Wt,
                                            const void* __restrict__ Wf,
                                            u16* __restrict__ WT,
                                            u16* __restrict__ WtT,
                                            u16* __restrict__ WfT,
                                            u16* __restrict__ xb,
                                            float* __restrict__ wacc,
                                            float* __restrict__ ropeT,
                                            int usexb) {
    __shared__ u16 tls[32][33];
    int bid = blockIdx.x;
    if (bid < 5184) {                         // Wq/Wk/Wv transpose (768 x 2304)
        int fl = detect_fl(x);
        int z = bid / 1728, t = bid % 1728;
        const void* W = (z == 0) ? Wq : (z == 1) ? Wk : Wv;
        do_transpose(W, WT + (size_t)z * N3 * 768, 768, N3,
                     (t % 72) * 32, (t / 72) * 32, fl, tls);
        return;
    }
    bid -= 5184;
    if (bid < 3456) {                         // Wt/Wf transpose (2304 x 768)
        int fl = detect_fl(x);
        int z = bid / 1728, t = bid % 1728;
        do_transpose(z ? Wf : Wt, z ? WfT : WtT, N3, 768,
                     (t % 24) * 32, (t / 24) * 32, fl, tls);
        return;
    }
    bid -= 3456;
    if (bid < 9411) {                         // x -> bf16 (exact 2409216 thr)
        if (!usexb) return;
        int fl = detect_fl(x);
        size_t e0 = ((size_t)bid * 256 + threadIdx.x) * 8;
        if (fl) {
            const float* p = (const float*)x + e0;
            float4 u0 = *(const float4*)p, u1 = *(const float4*)(p + 4);
            short8 r;
            r[0]=(short)f2b(u0.x); r[1]=(short)f2b(u0.y); r[2]=(short)f2b(u0.z); r[3]=(short)f2b(u0.w);
            r[4]=(short)f2b(u1.x); r[5]=(short)f2b(u1.y); r[6]=(short)f2b(u1.z); r[7]=(short)f2b(u1.w);
            *(short8*)(xb + e0) = r;
        } else {
            *(short8*)(xb + e0) = *(const short8*)(x + e0);
        }
        return;
    }
    bid -= 9411;
    if (bid < 1176) {                         // wacc zero (exact 301056)
        wacc[(size_t)bid * 256 + threadIdx.x] = 0.f;
        return;
    }
    bid -= 1176;
    {                                         // rope table (exact 100352)
        int t = bid * 256 + threadIdx.x;
        int s = t >> 5, i = t & 31;
        float inv = powf(10000.0f, -(float)(2 * i) * (1.0f / 64.0f));
        float sn, cs;
        sincosf((float)s * inv, &sn, &cs);
        ropeT[t * 2]     = cs;
        ropeT[t * 2 + 1] = sn;
    }
}

// --------------------------------- GEMM ------------------------------------
DEV short8 pack_f32x8(const float* p) {
    const float4 u0 = *(const float4*)p;
    const float4 u1 = *(const float4*)(p + 4);
    short8 r;
    r[0]=(short)f2b(u0.x); r[1]=(short)f2b(u0.y); r[2]=(short)f2b(u0.z); r[3]=(short)f2b(u0.w);
    r[4]=(short)f2b(u1.x); r[5]=(short)f2b(u1.y); r[6]=(short)f2b(u1.z); r[7]=(short)f2b(u1.w);
    return r;
}

__global__ __launch_bounds__(256) void gemm_bt(const void* __restrict__ A, size_t aoff,
                                               const u16* __restrict__ BT,
                                               const void* __restrict__ b0p,
                                               const void* __restrict__ b1p,
                                               const void* __restrict__ b2p,
                                               void* __restrict__ C,
                                               int M, int N, int K,
                                               const u16* __restrict__ xdet,
                                               int araw, int cf32) {
    const int fl = detect_fl(xdet);
    const int af32 = araw && fl;
    const int z = blockIdx.z;
    const u16* Bz = BT + (size_t)z * N * K;
    const void* bias = (z == 0) ? b0p : (z == 1) ? b1p : b2p;

    __shared__ u16 As[128 * 32];
    __shared__ u16 Bs[128 * 32];

    const int tid  = threadIdx.x;
    const int lane = tid & 63;
    const int wave = tid >> 6;
    const int wm   = wave & 1;
    const int wn   = wave >> 1;
    const int quad = lane >> 4;
    const int l16  = lane & 15;

    const int m0 = blockIdx.y * 128;
    const int n0 = blockIdx.x * 128;

    f32x4 acc[4][4] = {};

    if (!af32) {
        const u16* Ab = (const u16*)A + aoff;
        int srow = wave * 32 + (lane >> 2);
        int scol = (lane & 3) * 8;
        int ar0 = m0 + srow;      if (ar0 > M - 1) ar0 = M - 1;
        int ar1 = m0 + srow + 16; if (ar1 > M - 1) ar1 = M - 1;
        const u16* gA0 = Ab + (size_t)ar0 * K + scol;
        const u16* gA1 = Ab + (size_t)ar1 * K + scol;
        const u16* gB0 = Bz + (size_t)(n0 + srow) * K + scol;
        const u16* gB1 = Bz + (size_t)(n0 + srow + 16) * K + scol;
        u16* lA0 = As + wave * 1024;
        u16* lA1 = As + wave * 1024 + 512;
        u16* lB0 = Bs + wave * 1024;
        u16* lB1 = Bs + wave * 1024 + 512;

        for (int k0 = 0; k0 < K; k0 += 32) {
            __syncthreads();
            gld16(gA0 + k0, lA0);
            gld16(gA1 + k0, lA1);
            gld16(gB0 + k0, lB0);
            gld16(gB1 + k0, lB1);
            __syncthreads();

            short8 af[4], bfr[4];
#pragma unroll
            for (int i = 0; i < 4; i++)
                af[i] = *(const short8*)(&As[(wm * 64 + i * 16 + l16) * 32 + quad * 8]);
#pragma unroll
            for (int j = 0; j < 4; j++)
                bfr[j] = *(const short8*)(&Bs[(wn * 64 + j * 16 + l16) * 32 + quad * 8]);
#pragma unroll
            for (int i = 0; i < 4; i++)
#pragma unroll
                for (int j = 0; j < 4; j++)
                    acc[i][j] = __builtin_amdgcn_mfma_f32_16x16x32_bf16(af[i], bfr[j], acc[i][j], 0, 0, 0);
        }
    } else {
        const int r0 = tid >> 2;
        const int kp = (tid & 3) << 3;
        int ga0 = m0 + r0;       if (ga0 > M - 1) ga0 = M - 1;
        int ga1 = m0 + r0 + 64;  if (ga1 > M - 1) ga1 = M - 1;
        const size_t arow0 = aoff + (size_t)ga0 * K + kp;
        const size_t arow1 = aoff + (size_t)ga1 * K + kp;
        const u16* Bp0 = Bz + (size_t)(n0 + r0) * K + kp;
        const u16* Bp1 = Bz + (size_t)(n0 + r0 + 64) * K + kp;

        for (int k0 = 0; k0 < K; k0 += 32) {
            short8 a0 = pack_f32x8((const float*)A + arow0 + k0);
            short8 a1 = pack_f32x8((const float*)A + arow1 + k0);
            short8 bv0 = *(const short8*)(Bp0 + k0);
            short8 bv1 = *(const short8*)(Bp1 + k0);
            __syncthreads();
            *(short8*)(&As[r0 * 32 + kp])        = a0;
            *(short8*)(&As[(r0 + 64) * 32 + kp]) = a1;
            *(short8*)(&Bs[r0 * 32 + kp])        = bv0;
            *(short8*)(&Bs[(r0 + 64) * 32 + kp]) = bv1;
            __syncthreads();

            short8 af[4], bfr[4];
#pragma unroll
            for (int i = 0; i < 4; i++)
                af[i] = *(const short8*)(&As[(wm * 64 + i * 16 + l16) * 32 + quad * 8]);
#pragma unroll
            for (int j = 0; j < 4; j++)
                bfr[j] = *(const short8*)(&Bs[(wn * 64 + j * 16 + l16) * 32 + quad * 8]);
#pragma unroll
            for (int i = 0; i < 4; i++)
#pragma unroll
                for (int j = 0; j < 4; j++)
                    acc[i][j] = __builtin_amdgcn_mfma_f32_16x16x32_bf16(af[i], bfr[j], acc[i][j], 0, 0, 0);
        }
    }

#pragma unroll
    for (int j = 0; j < 4; j++) {
        int col = n0 + wn * 64 + j * 16 + l16;
        float bb = fl ? ((const float*)bias)[col] : b2f(((const u16*)bias)[col]);
#pragma unroll
        for (int i = 0; i < 4; i++) {
            int rowb = m0 + wm * 64 + i * 16 + quad * 4;
#pragma unroll
            for (int r = 0; r < 4; r++) {
                int row = rowb + r;
                if (row < M) {
                    size_t idx = (size_t)z * M * N + (size_t)row * N + col;
                    float v = acc[i][j][r] + bb;
                    if (cf32) ((float*)C)[idx] = v;
                    else      ((u16*)C)[idx]  = f2b(v);
                }
            }
        }
    }
}

// ------------------------- phase A attention (fused) -----------------------
// grid (227, 12, bs): x<195 -> temporal p=x+1; x>=195 -> cls split sp=x-195.
__global__ __launch_bounds__(256) void phaseA_attn(const u16* __restrict__ Pb, size_t PZv,
                                                   const float* __restrict__ tab,
                                                   u16* __restrict__ tmp,
                                                   float* __restrict__ clsP, int b0) {
    __shared__ __align__(16) char smem[40800];
    int xg = blockIdx.x, h = blockIdx.y, bl = blockIdx.z;
    int b = b0 + bl;
    int tid = threadIdx.x;

    if (xg < 195) {
        // ---------------- temporal attention ----------------
        int p = xg + 1;
        u16* Qs = (u16*)smem;                 // 16*LDK
        u16* Ks = Qs + 16 * LDK;
        u16* Vs = Ks + 16 * LDK;
        float* w = (float*)(smem + 3 * 16 * LDK * 2);
        const u16* Pq = Pb;            // z0 -> q
        const u16* Pk = Pb + 2 * PZv;  // z2 (Wv) -> k
        const u16* Pv = Pb + PZv;      // z1 (Wk) -> v
        const size_t rbase = (size_t)bl * ROWS;

        for (int i = tid; i < 384; i += 256) {
            int f = i / 24, c = (i % 24) * 8;
            int s = f * 196 + p;
            size_t gidx = (rbase + 1 + s) * N3 + (size_t)h * 192 + c;
            short8 q8 = *(const short8*)(Pq + gidx);
            short8 k8 = *(const short8*)(Pk + gidx);
            short8 v8 = *(const short8*)(Pv + gidx);
            if (c < 64) {
                const float* tp = tab + ((size_t)s * 32 + (c >> 1)) * 2;
                float4 t0 = *(const float4*)tp;
                float4 t1 = *(const float4*)(tp + 4);
                float cs[4] = {t0.x, t0.z, t1.x, t1.z};
                float sn[4] = {t0.y, t0.w, t1.y, t1.w};
                short8 qo, ko;
#pragma unroll
                for (int j = 0; j < 4; j++) {
                    float q1 = b2fs(q8[2 * j]), q2 = b2fs(q8[2 * j + 1]);
                    float k1 = b2fs(k8[2 * j]), k2 = b2fs(k8[2 * j + 1]);
                    qo[2 * j]     = (short)f2b(q1 * cs[j] - q2 * sn[j]);
                    qo[2 * j + 1] = (short)f2b(q2 * cs[j] + q1 * sn[j]);
                    ko[2 * j]     = (short)f2b(k1 * cs[j] - k2 * sn[j]);
                    ko[2 * j + 1] = (short)f2b(k2 * cs[j] + k1 * sn[j]);
                }
                q8 = qo; k8 = ko;
            }
            *(short8*)&Qs[f * LDK + c] = q8;
            *(short8*)&Ks[f * LDK + c] = k8;
            *(short8*)&Vs[f * LDK + c] = v8;
        }
        __syncthreads();

        if (tid < 64) {
            int quad = tid >> 4, l16 = tid & 15;
            short8 Af[6], Bf[6];
#pragma unroll
            for (int ks = 0; ks < 6; ks++) {
                Af[ks] = *(const short8*)&Qs[l16 * LDK + quad * 8 + ks * 32];
                Bf[ks] = *(const short8*)&Ks[l16 * LDK + quad * 8 + ks * 32];
            }
            f32x4 S = {0.f, 0.f, 0.f, 0.f};
#pragma unroll
            for (int ks = 0; ks < 6; ks++)
                S = __builtin_amdgcn_mfma_f32_16x16x32_bf16(Af[ks], Bf[ks], S, 0, 0, 0);
            float wcol = 0.f;
#pragma unroll
            for (int r = 0; r < 4; r++) {
                float v = S[r] * SCALE;
                float m = v;
#pragma unroll
                for (int k = 1; k < 16; k <<= 1) m = fmaxf(m, __shfl_xor(m, k));
                float e = __expf(v - m);
                float l = e;
#pragma unroll
                for (int k = 1; k < 16; k <<= 1) l += __shfl_xor(l, k);
                wcol += e / l;
            }
            wcol += __shfl_xor(wcol, 16);
            wcol += __shfl_xor(wcol, 32);
            if (quad == 0) w[l16] = wcol;
        }
        __syncthreads();

        if (tid < 192) {
            float acc = 0.f;
#pragma unroll
            for (int g = 0; g < 16; g++) acc += w[g] * b2f(Vs[g * LDK + tid]);
            tmp[(size_t)(b * NPm1 + p - 1) * N3 + (size_t)h * 192 + tid] = f2b(acc);
        }
    } else {
        // ---------------- cls partial (online softmax slice) ----------------
        int sp = xg - 195;
        int base = sp * CLS_RS;
        int cnt = ROWS - base; if (cnt > CLS_RS) cnt = CLS_RS;
        u16* Ksh  = (u16*)smem;                            // 99*LDK = 39600 B
        float* qs  = (float*)(smem + CLS_RS * LDK * 2);    // 192 f
        float* sc  = qs + 192;                             // 100 f
        float* red = sc + 100;                             // 4 f
        const size_t hbase = (size_t)bl * ROWS * N3 + (size_t)h * 192;
        const u16* Pq  = Pb;            // z0
        const u16* Pkc = Pb + PZv;      // z1 (Wk) -> k_cls
        const u16* Pvc = Pb + 2 * PZv;  // z2 (Wv) -> v_cls

        if (tid < 192) qs[tid] = b2f(Pq[hbase + tid]);
        for (int i = tid; i < cnt * 24; i += 256) {
            int r = i / 24, c = (i % 24) * 8;
            *(short8*)&Ksh[r * LDK + c] =
                *(const short8*)(Pkc + hbase + (size_t)(base + r) * N3 + c);
        }
        __syncthreads();

        float sval = -1e30f;
        if (tid < cnt) {
            float s = 0.f;
#pragma unroll
            for (int c = 0; c < 24; c++) {
                short8 v8 = *(const short8*)&Ksh[tid * LDK + c * 8];
#pragma unroll
                for (int j = 0; j < 8; j++) s += qs[c * 8 + j] * b2fs(v8[j]);
            }
            sval = s * SCALE;
        }
        float m = block_max256(sval, red);
        float e = (tid < cnt) ? __expf(sval - m) : 0.f;
        float l = block_sum256(e, red);
        if (tid < cnt) sc[tid] = e;
        __syncthreads();

        float* pp = clsP + ((size_t)(b * 12 + h) * CLS_NS + sp) * 194;
        if (tid == 0) { pp[0] = m; pp[1] = l; }
        if (tid < 192) {
            float acc = 0.f;
            const u16* vb = Pvc + hbase + tid;
            for (int r = 0; r < cnt; r++) acc += sc[r] * b2f(vb[(size_t)(base + r) * N3]);
            pp[2 + tid] = acc;
        }
    }
}

// ------------------------- second attention scores -------------------------
__global__ __launch_bounds__(256) void attn2_sc(const u16* __restrict__ P2,
                                                float* __restrict__ wacc) {
    int t = blockIdx.x, h = blockIdx.y, b = blockIdx.z;
    __shared__ u16 Ks[195 * LDK];
    __shared__ u16 Qs[31 * LDK];
    __shared__ float pm[4][16], ps[4][16];
    int tid = threadIdx.x;
    const size_t hb = (size_t)b * NPm1 * N3 + (size_t)h * 192;
    const u16* Q  = P2;             // z0 -> q2
    const u16* Kc = P2 + 2 * P2Z;   // z2 (Wv) -> k2

    for (int i = tid; i < 195 * 24; i += 256) {
        int r = i / 24, c = (i % 24) * 8;
        *(short8*)&Ks[r * LDK + c] = *(const short8*)(Kc + hb + (size_t)r * N3 + c);
    }
    for (int i = tid; i < 31 * 24; i += 256) {
        int r = i / 24, c = (i % 24) * 8;
        int qr = (t * 16 + r) % 195;
        *(short8*)&Qs[r * LDK + c] = *(const short8*)(Q + hb + (size_t)qr * N3 + c);
    }
    __syncthreads();

    int wave = tid >> 6, lane = tid & 63, quad = lane >> 4, l16 = lane & 15;
    float* wb = wacc + (size_t)((b * 12 + h) * 16) * 196;

    for (int xi = 1 + wave; xi <= 15; xi += 4) {
        short8 Af[6], Bf[6];
#pragma unroll
        for (int ks = 0; ks < 6; ks++) {
            Af[ks] = *(const short8*)&Qs[(xi + l16) * LDK + quad * 8 + ks * 32];
            Bf[ks] = *(const short8*)&Ks[(xi + l16) * LDK + quad * 8 + ks * 32];
        }
        f32x4 S = {0.f, 0.f, 0.f, 0.f};
#pragma unroll
        for (int ks = 0; ks < 6; ks++)
            S = __builtin_amdgcn_mfma_f32_16x16x32_bf16(Af[ks], Bf[ks], S, 0, 0, 0);
        float wcol = 0.f;
#pragma unroll
        for (int r = 0; r < 4; r++) {
            float v = S[r] * SCALE;
            float m = v;
#pragma unroll
            for (int k = 1; k < 16; k <<= 1) m = fmaxf(m, __shfl_xor(m, k));
            float e = __expf(v - m);
            float l = e;
#pragma unroll
            for (int k = 1; k < 16; k <<= 1) l += __shfl_xor(l, k);
            bool qok = (t * 16 + quad * 4 + r) <= 195;
            wcol += qok ? e / l : 0.f;
        }
        wcol += __shfl_xor(wcol, 16);
        wcol += __shfl_xor(wcol, 32);
        if (quad == 0) atomicAdd(&wb[xi * 196 + l16], wcol);
    }

    short8 Af0[6];
#pragma unroll
    for (int ks = 0; ks < 6; ks++)
        Af0[ks] = *(const short8*)&Qs[l16 * LDK + quad * 8 + ks * 32];

    f32x4 Sc[4];
    int   cl[4];
    int   cn = 0;
    for (int c = wave; c < 13; c += 4) {
        int g = c * 16 + l16;
        int krow = g % 195;
        short8 Bf[6];
#pragma unroll
        for (int ks = 0; ks < 6; ks++)
            Bf[ks] = *(const short8*)&Ks[krow * LDK + quad * 8 + ks * 32];
        f32x4 S = {0.f, 0.f, 0.f, 0.f};
#pragma unroll
        for (int ks = 0; ks < 6; ks++)
            S = __builtin_amdgcn_mfma_f32_16x16x32_bf16(Af0[ks], Bf[ks], S, 0, 0, 0);
        bool kbad = g > 195;
#pragma unroll
        for (int r = 0; r < 4; r++) S[r] = kbad ? -1e30f : S[r] * SCALE;
        Sc[cn] = S; cl[cn] = c; cn++;
    }
#pragma unroll
    for (int r = 0; r < 4; r++) {
        float v = -1e30f;
        for (int n = 0; n < cn; n++) v = fmaxf(v, Sc[n][r]);
#pragma unroll
        for (int k = 1; k < 16; k <<= 1) v = fmaxf(v, __shfl_xor(v, k));
        if (l16 == 0) pm[wave][quad * 4 + r] = v;
    }
    __syncthreads();
    float gmx[4], tot[4];
#pragma unroll
    for (int r = 0; r < 4; r++) {
        int qr = quad * 4 + r;
        gmx[r] = fmaxf(fmaxf(pm[0][qr], pm[1][qr]), fmaxf(pm[2][qr], pm[3][qr]));
    }
#pragma unroll
    for (int r = 0; r < 4; r++) {
        float s = 0.f;
        for (int n = 0; n < cn; n++) {
            float e = __expf(Sc[n][r] - gmx[r]);
            Sc[n][r] = e;
            s += e;
        }
#pragma unroll
        for (int k = 1; k < 16; k <<= 1) s += __shfl_xor(s, k);
        if (l16 == 0) ps[wave][quad * 4 + r] = s;
    }
    __syncthreads();
#pragma unroll
    for (int r = 0; r < 4; r++) {
        int qr = quad * 4 + r;
        tot[r] = (ps[0][qr] + ps[1][qr]) + (ps[2][qr] + ps[3][qr]);
    }
    for (int n = 0; n < cn; n++) {
        float wv = 0.f;
#pragma unroll
        for (int r = 0; r < 4; r++) {
            bool qok = (t * 16 + quad * 4 + r) <= 195;
            wv += qok ? Sc[n][r] / tot[r] : 0.f;
        }
        wv += __shfl_xor(wv, 16);
        wv += __shfl_xor(wv, 32);
        int g = cl[n] * 16 + l16;
        if (quad == 0 && g <= 195) atomicAdd(&wb[g], wv);
    }
}

// ----------------------- fin: cls merge + attn2 epilogue -------------------
// grid (17, 12, 8): x==0 -> cls merge; x>=1 -> attn2_fin xi=x-1.
__global__ __launch_bounds__(192) void fin(const u16* __restrict__ P2,
                                           const float* __restrict__ wacc,
                                           const float* __restrict__ clsP,
                                           u16* __restrict__ Fmat) {
    int xg = blockIdx.x, h = blockIdx.y, b = blockIdx.z;
    int tid = threadIdx.x;
    if (xg == 0) {
        const float* p0 = clsP + (size_t)(b * 12 + h) * CLS_NS * 194;
        float M = -1e30f;
#pragma unroll
        for (int s = 0; s < CLS_NS; s++) M = fmaxf(M, p0[s * 194]);
        float L = 0.f, acc = 0.f;
#pragma unroll
        for (int s = 0; s < CLS_NS; s++) {
            float w = __expf(p0[s * 194] - M);
            L += w * p0[s * 194 + 1];
            acc += w * p0[s * 194 + 2 + tid];
        }
        Fmat[(size_t)(b * 17) * N3 + (size_t)h * 192 + tid] = f2b(acc / L);
    } else {
        int xi = xg - 1;
        int Nk = (xi == 0) ? 196 : 16;
        const u16* V = P2 + P2Z;        // z1 (Wk) -> v2
        const size_t hb = (size_t)b * NPm1 * N3 + (size_t)h * 192;
        const float* wb = wacc + (size_t)((b * 12 + h) * 16 + xi) * 196;
        float acc = 0.f;
        for (int g = 0; g < Nk; g++) {
            int kr = (xi == 0) ? (g % 195) : (xi + g);
            acc += wb[g] * b2f(V[hb + (size_t)kr * N3 + tid]);
        }
        Fmat[(size_t)(b * 17 + 1 + xi) * N3 + (size_t)h * 192 + tid] = f2b(acc);
    }
}

// ------------------------------ final scatter ------------------------------
__global__ __launch_bounds__(256) void scatter_out(const float* __restrict__ F17,
                                                   void* __restrict__ out,
                                                   const u16* __restrict__ xdet) {
    const int fl = detect_fl(xdet);
    int t = blockIdx.x * 256 + threadIdx.x;   // < 8*3137*96 exactly
    int c = t % 96;
    int rem = t / 96;
    int s = rem % ROWS;
    int b = rem / ROWS;
    int src = b * 17 + (s == 0 ? 0 : 1 + ((s - 1) & 15));
    const float* sp = F17 + ((size_t)src * 96 + c) * 8;
    if (fl) {
        float* o = (float*)out + (size_t)t * 8;
        *(float4*)o       = *(const float4*)sp;
        *(float4*)(o + 4) = *(const float4*)(sp + 4);
    } else {
        u16* o = (u16*)out + (size_t)t * 8;
        short8 v;
#pragma unroll
        for (int j = 0; j < 8; j++) v[j] = (short)f2b(sp[j]);
        *(short8*)o = v;
    }
}

// ------------------------------ host launcher ------------------------------
extern "C" void kernel_launch(void* const* d_in, const int* in_sizes, int n_in,
                              void* d_out, int out_size, void* d_ws, size_t ws_size,
                              hipStream_t stream) {
    const void* x   = d_in[0];
    const void* Wq  = d_in[1];
    const void* bq  = d_in[2];
    const void* Wk  = d_in[3];
    const void* bk  = d_in[4];
    const void* Wv  = d_in[5];
    const void* bv  = d_in[6];
    const void* Wt  = d_in[7];
    const void* bt  = d_in[8];
    const void* Wf  = d_in[9];
    const void* bfb = d_in[10];
    const u16* xdet = (const u16*)x;
    (void)in_sizes; (void)n_in; (void)out_size;

    auto al = [](size_t b) { return (b + 255) & ~(size_t)255; };
    const size_t szWT   = al((size_t)3 * N3 * 768 * 2);
    const size_t szWtT  = al((size_t)768 * N3 * 2);
    const size_t szTmp  = al((size_t)MT * N3 * 2);
    const size_t szFmat = al((size_t)136 * N3 * 2);
    const size_t szRope = al((size_t)3136 * 32 * 2 * 4);
    const size_t szClsP = al((size_t)8 * 12 * CLS_NS * 194 * 4);
    const size_t szWacc = al((size_t)96 * 16 * 196 * 4);
    const size_t szXb   = al((size_t)8 * ROWS * 768 * 2);
    const size_t szB    = al(3 * P2Z * 2) + al((size_t)MT * 768 * 2) +
                          al((size_t)136 * 768 * 4);
    const size_t basePerst = szWT + 2 * szWtT + szTmp + szFmat + szRope + szClsP + szWacc;

    int bs = 1; int usexb = 0;
    {
        const int cand[4] = {8, 4, 2, 1};
        for (int i = 0; i < 4; i++) {
            size_t szP = al((size_t)3 * cand[i] * ROWS * N3 * 2);
            size_t need = basePerst + szXb + (szP > szB ? szP : szB);
            if (ws_size >= need) { bs = cand[i]; usexb = 1; break; }
        }
        if (!usexb) {
            size_t szP = al((size_t)3 * ROWS * N3 * 2);
            size_t need = basePerst + (szP > szB ? szP : szB);
            if (ws_size < need) return;   // graceful mismatch instead of fault
        }
    }

    char* ws = (char*)d_ws;
    size_t off = 0;
    auto allocB = [&](size_t bytes) { char* p = ws + off; off += al(bytes); return p; };
    u16*   WT    = (u16*)allocB((size_t)3 * N3 * 768 * 2);
    u16*   WtT   = (u16*)allocB((size_t)768 * N3 * 2);
    u16*   WfT   = (u16*)allocB((size_t)768 * N3 * 2);
    u16*   tmp   = (u16*)allocB((size_t)MT * N3 * 2);
    u16*   Fmat  = (u16*)allocB((size_t)136 * N3 * 2);
    float* ropeT = (float*)allocB((size_t)3136 * 32 * 2 * 4);
    float* clsP  = (float*)allocB((size_t)8 * 12 * CLS_NS * 194 * 4);
    float* wacc  = (float*)allocB((size_t)96 * 16 * 196 * 4);
    u16*   xb    = usexb ? (u16*)allocB((size_t)8 * ROWS * 768 * 2) : nullptr;
    size_t aliasOff = off;
    u16* Pb = (u16*)allocB((size_t)3 * bs * ROWS * N3 * 2);
    off = aliasOff;                                     // phase B aliases Pb
    u16*   P2  = (u16*)allocB(3 * P2Z * 2);
    u16*   tiu = (u16*)allocB((size_t)MT * 768 * 2);
    float* F17 = (float*)allocB((size_t)136 * 768 * 4);

    const size_t PZv = (size_t)bs * ROWS * N3;

    // 1. prep: transposes + convert + wacc zero + rope  (19619 blocks)
    prep<<<dim3(19619), 256, 0, stream>>>(xdet, Wq, Wk, Wv, Wt, Wf,
                                          WT, WtT, WfT, xb, wacc, ropeT, usexb);

    // 2..: phase A
    for (int b0 = 0; b0 < 8; b0 += bs) {
        int Mv = bs * ROWS;
        size_t aoff = (size_t)b0 * ROWS * 768;
        if (usexb)
            gemm_bt<<<dim3(18, (Mv + 127) / 128, 3), 256, 0, stream>>>(
                xb, aoff, WT, bq, bk, bv, Pb, Mv, N3, 768, xdet, 0, 0);
        else
            gemm_bt<<<dim3(18, (Mv + 127) / 128, 3), 256, 0, stream>>>(
                x, aoff, WT, bq, bk, bv, Pb, Mv, N3, 768, xdet, 1, 0);
        phaseA_attn<<<dim3(227, 12, bs), 256, 0, stream>>>(Pb, PZv, ropeT, tmp, clsP, b0);
    }

    // phase B
    gemm_bt<<<dim3(6, 13, 1), 256, 0, stream>>>(tmp, 0, WtT, bt, bt, bt, tiu,
                                                MT, 768, N3, xdet, 0, 0);
    gemm_bt<<<dim3(18, 13, 3), 256, 0, stream>>>(tiu, 0, WT, bq, bk, bv, P2,
                                                 MT, N3, 768, xdet, 0, 0);
    attn2_sc<<<dim3(13, 12, 8), 256, 0, stream>>>(P2, wacc);
    fin<<<dim3(17, 12, 8), 192, 0, stream>>>(P2, wacc, clsP, Fmat);
    gemm_bt<<<dim3(6, 2, 1), 256, 0, stream>>>(Fmat, 0, WfT, bfb, bfb, bfb, F17,
                                               136, 768, N3, xdet, 0, 1);
    scatter_out<<<dim3(9411), 256, 0, stream>>>(F17, d_out, xdet);
}